// Round 1
// baseline (4225.700 us; speedup 1.0000x reference)
//
#include <hip/hip_runtime.h>
#include <hip/hip_bf16.h>
#include <math.h>

// Problem constants
#define B_    2
#define L_    2048
#define DM_   1024      // d_model
#define DI_   2048      // d_inner
#define DS_   16        // d_state
#define DTR_  64        // dt_rank
#define NXZ_  4096      // 2*d_inner
#define NDBC_ 96        // dt_rank + 2*d_state

// GEMM tiling
#define TM 64
#define TN 64
#define TK 16

#define EPI_NONE     0
#define EPI_SOFTPLUS 1
#define EPI_OUT_FW   2
#define EPI_OUT_BW   3

// ---------------- LayerNorm (one block per row) ----------------
__global__ __launch_bounds__(256)
void ln_kernel(const float* __restrict__ x,
               const float* __restrict__ gamma,
               const float* __restrict__ beta,
               float* __restrict__ out)
{
    int row = blockIdx.x;          // 0..B*L-1
    int t = threadIdx.x;           // 256 threads, 4 floats each
    const float* xr = x + (size_t)row * DM_;
    float4 v = ((const float4*)xr)[t];
    float s  = v.x + v.y + v.z + v.w;
    float ss = v.x*v.x + v.y*v.y + v.z*v.z + v.w*v.w;
    #pragma unroll
    for (int m = 1; m < 64; m <<= 1) {
        s  += __shfl_xor(s,  m, 64);
        ss += __shfl_xor(ss, m, 64);
    }
    __shared__ float as_[4], ass_[4];
    int w = t >> 6;
    if ((t & 63) == 0) { as_[w] = s; ass_[w] = ss; }
    __syncthreads();
    s  = as_[0] + as_[1] + as_[2] + as_[3];
    ss = ass_[0] + ass_[1] + ass_[2] + ass_[3];
    float mu  = s * (1.0f / DM_);
    float var = ss * (1.0f / DM_) - mu * mu;
    float inv = rsqrtf(var + 1e-5f);
    float4 g  = ((const float4*)gamma)[t];
    float4 bt = ((const float4*)beta)[t];
    float4 o;
    o.x = (v.x - mu) * inv * g.x + bt.x;
    o.y = (v.y - mu) * inv * g.y + bt.y;
    o.z = (v.z - mu) * inv * g.z + bt.z;
    o.w = (v.w - mu) * inv * g.w + bt.w;
    ((float4*)(out + (size_t)row * DM_))[t] = o;
}

// ---------------- Generic fp32 tiled GEMM: C = A(MxK) @ W(NxK)^T ----------------
// flipA: read A rows seq-flipped (bw in_proj). epi: epilogue select.
__global__ __launch_bounds__(256)
void gemm_kernel(const float* __restrict__ A, int lda,
                 const float* __restrict__ W, int ldw,
                 float* __restrict__ C, int ldc,
                 const float* __restrict__ bias,
                 const float* __restrict__ resid,
                 int M, int N, int K, int flipA, int epi)
{
    __shared__ float sA[TK][TM + 1];
    __shared__ float sW[TK][TN + 1];
    int t  = threadIdx.x;
    int tx = t & 15, ty = t >> 4;
    int m0 = blockIdx.y * TM, n0 = blockIdx.x * TN;
    float acc[4][4] = {};
    for (int k0 = 0; k0 < K; k0 += TK) {
        #pragma unroll
        for (int p = 0; p < 4; ++p) {
            int e = t + p * 256;
            int kk = e & 15, rr = e >> 4;
            int gr = m0 + rr, gk = k0 + kk;
            int ar = gr;
            if (flipA) { int b = gr >> 11, l = gr & (L_ - 1); ar = (b << 11) + (L_ - 1 - l); }
            sA[kk][rr] = (gr < M && gk < K) ? A[(size_t)ar * lda + gk] : 0.f;
        }
        #pragma unroll
        for (int p = 0; p < 4; ++p) {
            int e = t + p * 256;
            int kk = e & 15, rr = e >> 4;
            int gn = n0 + rr, gk = k0 + kk;
            sW[kk][rr] = (gn < N && gk < K) ? W[(size_t)gn * ldw + gk] : 0.f;
        }
        __syncthreads();
        #pragma unroll
        for (int k = 0; k < TK; ++k) {
            float a[4], w[4];
            #pragma unroll
            for (int i = 0; i < 4; ++i) a[i] = sA[k][ty * 4 + i];
            #pragma unroll
            for (int j = 0; j < 4; ++j) w[j] = sW[k][tx * 4 + j];
            #pragma unroll
            for (int i = 0; i < 4; ++i)
                #pragma unroll
                for (int j = 0; j < 4; ++j)
                    acc[i][j] = fmaf(a[i], w[j], acc[i][j]);
        }
        __syncthreads();
    }
    #pragma unroll
    for (int i = 0; i < 4; ++i) {
        int gm = m0 + ty * 4 + i;
        if (gm >= M) continue;
        #pragma unroll
        for (int j = 0; j < 4; ++j) {
            int gn = n0 + tx * 4 + j;
            if (gn >= N) continue;
            float v = acc[i][j];
            if (epi == EPI_NONE) {
                C[(size_t)gm * ldc + gn] = v;
            } else if (epi == EPI_SOFTPLUS) {
                v += bias[gn];
                C[(size_t)gm * ldc + gn] = (v > 20.f) ? v : log1pf(__expf(v));
            } else if (epi == EPI_OUT_FW) {
                C[(size_t)gm * ldc + gn] = resid[(size_t)gm * ldc + gn] + 0.5f * v;
            } else { // EPI_OUT_BW: flip row on write, accumulate
                int b = gm >> 11, l = gm & (L_ - 1);
                int gr = (b << 11) + (L_ - 1 - l);
                C[(size_t)gr * ldc + gn] += 0.5f * v;
            }
        }
    }
}

// ---------------- Causal depthwise conv (width 4) + bias + SiLU ----------------
// Reads u0 = xz[..., 0:DI_] (row stride NXZ_), writes dense u (row stride DI_).
__global__ __launch_bounds__(256)
void conv_kernel(const float* __restrict__ xz,
                 const float* __restrict__ cw,
                 const float* __restrict__ cb,
                 float* __restrict__ u)
{
    int e = blockIdx.x * 256 + threadIdx.x;   // B*L*DI
    int d = e & (DI_ - 1);
    int l = (e >> 11) & (L_ - 1);
    int b = e >> 22;
    float4 wv = ((const float4*)cw)[d];
    float acc = cb[d];
    size_t base = ((size_t)b * L_) * NXZ_ + d;
    if (l >= 3) acc += wv.x * xz[base + (size_t)(l - 3) * NXZ_];
    if (l >= 2) acc += wv.y * xz[base + (size_t)(l - 2) * NXZ_];
    if (l >= 1) acc += wv.z * xz[base + (size_t)(l - 1) * NXZ_];
    acc += wv.w * xz[base + (size_t)l * NXZ_];
    u[e] = acc / (1.f + __expf(-acc));   // silu
}

// ---------------- Selective scan ----------------
// Thread layout: lane s = t&15 owns state s of channel d = d0 + (t>>4).
// LDS-chunked over 64 timesteps. Writes y in-place over dt buffer.
#define CHUNK 64
__global__ __launch_bounds__(256)
void scan_kernel(float* __restrict__ dty,        // in: dt, out: y
                 const float* __restrict__ u,
                 const float* __restrict__ xz,   // z = xz[row*NXZ_ + DI_ + d]
                 const float* __restrict__ dbc,
                 const float* __restrict__ A_log,
                 const float* __restrict__ Dskip)
{
    __shared__ float sdt[CHUNK][16], su[CHUNK][16], sz[CHUNK][16];
    __shared__ float sB[CHUNK][16], sC[CHUNK][16], sy[CHUNK][16];
    int t = threadIdx.x;
    int s = t & 15, dloc = t >> 4;
    int d0 = blockIdx.x * 16;
    int b  = blockIdx.y;
    int d  = d0 + dloc;
    float A_ds = -__expf(A_log[d * DS_ + s]);
    float Dd   = Dskip[d];
    float h = 0.f;
    size_t rowbase = (size_t)b * L_;
    for (int l0 = 0; l0 < L_; l0 += CHUNK) {
        #pragma unroll
        for (int p = 0; p < 4; ++p) {
            int e = t + p * 256;
            int ll = e >> 4, dd = e & 15;
            size_t r = rowbase + l0 + ll;
            sdt[ll][dd] = dty[r * DI_ + d0 + dd];
            su[ll][dd]  = u[r * DI_ + d0 + dd];
            sz[ll][dd]  = xz[r * NXZ_ + DI_ + d0 + dd];
            sB[ll][dd]  = dbc[r * NDBC_ + DTR_ + dd];
            sC[ll][dd]  = dbc[r * NDBC_ + DTR_ + DS_ + dd];
        }
        __syncthreads();
        for (int l = 0; l < CHUNK; ++l) {
            float dt = sdt[l][dloc];
            float uu = su[l][dloc];
            float Bt = sB[l][s];
            float Ct = sC[l][s];
            float dA = __expf(dt * A_ds);
            h = dA * h + (dt * uu) * Bt;
            float py = h * Ct;
            py += __shfl_xor(py, 1, 16);
            py += __shfl_xor(py, 2, 16);
            py += __shfl_xor(py, 4, 16);
            py += __shfl_xor(py, 8, 16);
            if (s == 0) {
                float z = sz[l][dloc];
                sy[l][dloc] = (py + Dd * uu) * (z / (1.f + __expf(-z)));
            }
        }
        __syncthreads();
        #pragma unroll
        for (int p = 0; p < 4; ++p) {
            int e = t + p * 256;
            int ll = e >> 4, dd = e & 15;
            size_t r = rowbase + l0 + ll;
            dty[r * DI_ + d0 + dd] = sy[ll][dd];
        }
        // next-iteration loads write sdt..sC only; sy rewritten after the
        // post-load __syncthreads() -> 2 barriers per chunk suffice.
    }
}

extern "C" void kernel_launch(void* const* d_in, const int* in_sizes, int n_in,
                              void* d_out, int out_size, void* d_ws, size_t ws_size,
                              hipStream_t stream)
{
    const float* x     = (const float*)d_in[0];
    const float* gamma = (const float*)d_in[1];
    const float* beta  = (const float*)d_in[2];
    float* out = (float*)d_out;

    // workspace layout (floats): needs ~146 MB
    float* ws  = (float*)d_ws;
    float* ln  = ws;                                  // B*L*DM     = 4,194,304
    float* xz  = ln  + (size_t)B_ * L_ * DM_;         // B*L*NXZ    = 16,777,216
    float* u   = xz  + (size_t)B_ * L_ * NXZ_;        // B*L*DI     = 8,388,608
    float* dt  = u   + (size_t)B_ * L_ * DI_;         // B*L*DI     = 8,388,608
    float* dbc = dt  + (size_t)B_ * L_ * DI_;         // B*L*NDBC   = 393,216

    dim3 blk(256);
    ln_kernel<<<B_ * L_, blk, 0, stream>>>(x, gamma, beta, ln);

    for (int dir = 0; dir < 2; ++dir) {
        int base = 3 + dir * 9;
        const float* in_w    = (const float*)d_in[base + 0];
        const float* conv_w  = (const float*)d_in[base + 1];
        const float* conv_b  = (const float*)d_in[base + 2];
        const float* xproj_w = (const float*)d_in[base + 3];
        const float* dt_w    = (const float*)d_in[base + 4];
        const float* dt_b    = (const float*)d_in[base + 5];
        const float* A_log   = (const float*)d_in[base + 6];
        const float* Dsk     = (const float*)d_in[base + 7];
        const float* out_w   = (const float*)d_in[base + 8];

        // in_proj: xz = ln(flip?) @ in_w^T   (M=4096, N=4096, K=1024)
        gemm_kernel<<<dim3(NXZ_ / TN, (B_ * L_) / TM), blk, 0, stream>>>(
            ln, DM_, in_w, DM_, xz, NXZ_, nullptr, nullptr,
            B_ * L_, NXZ_, DM_, dir, EPI_NONE);

        // causal depthwise conv + silu -> u
        conv_kernel<<<(B_ * L_ * DI_) / 256, blk, 0, stream>>>(xz, conv_w, conv_b, u);

        // xproj: dbc = u @ xproj_w^T   (M=4096, N=96, K=2048)
        gemm_kernel<<<dim3((NDBC_ + TN - 1) / TN, (B_ * L_) / TM), blk, 0, stream>>>(
            u, DI_, xproj_w, DI_, dbc, NDBC_, nullptr, nullptr,
            B_ * L_, NDBC_, DI_, 0, EPI_NONE);

        // dt = softplus(dbc[:, :64] @ dt_w^T + dt_b)   (M=4096, N=2048, K=64)
        gemm_kernel<<<dim3(DI_ / TN, (B_ * L_) / TM), blk, 0, stream>>>(
            dbc, NDBC_, dt_w, DTR_, dt, DI_, dt_b, nullptr,
            B_ * L_, DI_, DTR_, 0, EPI_SOFTPLUS);

        // selective scan (y written in-place over dt), fused D-skip + silu(z) gate
        scan_kernel<<<dim3(DI_ / 16, B_), blk, 0, stream>>>(dt, u, xz, dbc, A_log, Dsk);

        // out_proj + residual combine   (M=4096, N=1024, K=2048)
        gemm_kernel<<<dim3(DM_ / TN, (B_ * L_) / TM), blk, 0, stream>>>(
            dt, DI_, out_w, DI_, out, DM_, nullptr, x,
            B_ * L_, DM_, DI_, 0, dir ? EPI_OUT_BW : EPI_OUT_FW);
    }
}

// Round 2
// 1936.621 us; speedup vs baseline: 2.1820x; 2.1820x over previous
//
#include <hip/hip_runtime.h>
#include <hip/hip_bf16.h>
#include <math.h>

// Problem constants
#define B_    2
#define L_    2048
#define DM_   1024      // d_model
#define DI_   2048      // d_inner
#define DS_   16        // d_state
#define DTR_  64        // dt_rank
#define NXZ_  4096      // 2*d_inner
#define NDBC_ 96        // dt_rank + 2*d_state

typedef __attribute__((ext_vector_type(8))) short bf16x8;
typedef __attribute__((ext_vector_type(4))) float f32x4;

__device__ __forceinline__ void gload_lds16(const void* g, void* l) {
    __builtin_amdgcn_global_load_lds(
        (const __attribute__((address_space(1))) void*)g,
        (__attribute__((address_space(3))) void*)l,
        16, 0, 0);
}

// ---------------- LayerNorm (one block per row) -> bf16 out ----------------
__global__ __launch_bounds__(256)
void ln_kernel(const float* __restrict__ x,
               const float* __restrict__ gamma,
               const float* __restrict__ beta,
               __hip_bfloat16* __restrict__ out)
{
    int row = blockIdx.x;          // 0..B*L-1
    int t = threadIdx.x;           // 256 threads, 4 floats each
    const float* xr = x + (size_t)row * DM_;
    float4 v = ((const float4*)xr)[t];
    float s  = v.x + v.y + v.z + v.w;
    float ss = v.x*v.x + v.y*v.y + v.z*v.z + v.w*v.w;
    #pragma unroll
    for (int m = 1; m < 64; m <<= 1) {
        s  += __shfl_xor(s,  m, 64);
        ss += __shfl_xor(ss, m, 64);
    }
    __shared__ float as_[4], ass_[4];
    int w = t >> 6;
    if ((t & 63) == 0) { as_[w] = s; ass_[w] = ss; }
    __syncthreads();
    s  = as_[0] + as_[1] + as_[2] + as_[3];
    ss = ass_[0] + ass_[1] + ass_[2] + ass_[3];
    float mu  = s * (1.0f / DM_);
    float var = ss * (1.0f / DM_) - mu * mu;
    float inv = rsqrtf(var + 1e-5f);
    float4 g  = ((const float4*)gamma)[t];
    float4 bt = ((const float4*)beta)[t];
    __hip_bfloat16 ob[4];
    ob[0] = __float2bfloat16((v.x - mu) * inv * g.x + bt.x);
    ob[1] = __float2bfloat16((v.y - mu) * inv * g.y + bt.y);
    ob[2] = __float2bfloat16((v.z - mu) * inv * g.z + bt.z);
    ob[3] = __float2bfloat16((v.w - mu) * inv * g.w + bt.w);
    ((ushort4*)(out + (size_t)row * DM_))[t] = *(const ushort4*)ob;
}

// ---------------- fp32 -> bf16 convert ----------------
__global__ __launch_bounds__(256)
void cvt_kernel(const float* __restrict__ s, __hip_bfloat16* __restrict__ d, int n)
{
    int i = (blockIdx.x * 256 + threadIdx.x) * 4;
    if (i >= n) return;
    float4 v = *(const float4*)(s + i);
    __hip_bfloat16 ob[4];
    ob[0] = __float2bfloat16(v.x);
    ob[1] = __float2bfloat16(v.y);
    ob[2] = __float2bfloat16(v.z);
    ob[3] = __float2bfloat16(v.w);
    *(ushort4*)(d + i) = *(const ushort4*)ob;
}

// ---------------- bf16 MFMA GEMM: C = A(MxK) @ W(NxK)^T ----------------
// 128x128 tile, BK=64, global_load_lds staging with st-style XOR swizzle
// (linear LDS dest + inverse-swizzled global src + swizzled ds_read).
// epi: 0 = in_proj split (u0 fp32 for n<DI_, silu->bf16 zs for n>=DI_)
//      1 = out_fw : out = x + 0.5*v
//      2 = out_bw : out[fliprow] += 0.5*v
#define GBM 128
#define GBK 64
__global__ __launch_bounds__(256)
void mfma_gemm(const __hip_bfloat16* __restrict__ A, int lda,
               const __hip_bfloat16* __restrict__ W, int ldw,
               int K, int flipA, int epi,
               const float* __restrict__ xres,
               float* __restrict__ outF,
               float* __restrict__ u0o,
               __hip_bfloat16* __restrict__ zso)
{
    __shared__ __hip_bfloat16 smA[GBM * GBK];   // 16 KB
    __shared__ __hip_bfloat16 smB[GBM * GBK];   // 16 KB
    int t = threadIdx.x;
    int lane = t & 63, wid = t >> 6;
    int wm = wid >> 1, wn = wid & 1;            // 2x2 wave grid, 64x64 each
    int m0 = blockIdx.y * GBM, n0 = blockIdx.x * GBM;

    f32x4 acc[4][4];
    #pragma unroll
    for (int i = 0; i < 4; ++i)
        #pragma unroll
        for (int j = 0; j < 4; ++j)
            acc[i][j] = (f32x4){0.f, 0.f, 0.f, 0.f};

    // Precompute per-pass staging descriptors (row, col-byte) from the
    // involution l = o ^ (((o>>7)&7)<<4); rows are 128B (=BK*2) wide.
    int arows[4], brow_col[4];
    #pragma unroll
    for (int p = 0; p < 4; ++p) {
        int o = p * 4096 + t * 16;
        int l = o ^ (((o >> 7) & 7) << 4);
        int r = l >> 7, cb = l & 127;
        int gr = m0 + r;
        if (flipA) gr = (gr & ~(L_ - 1)) | ((L_ - 1) - (gr & (L_ - 1)));
        arows[p] = gr;
        brow_col[p] = (r << 8) | cb;   // pack
    }

    for (int k0 = 0; k0 < K; k0 += GBK) {
        #pragma unroll
        for (int p = 0; p < 4; ++p) {
            int o = p * 4096 + t * 16;
            int cb = brow_col[p] & 255;
            int r  = brow_col[p] >> 8;
            const char* gA = (const char*)(A + (size_t)arows[p] * lda + k0) + cb;
            gload_lds16(gA, (char*)smA + o);
            const char* gB = (const char*)(W + (size_t)(n0 + r) * ldw + k0) + cb;
            gload_lds16(gB, (char*)smB + o);
        }
        __syncthreads();   // drains vmcnt -> staged data visible

        #pragma unroll
        for (int ks = 0; ks < 2; ++ks) {
            bf16x8 af[4], bfv[4];
            #pragma unroll
            for (int f = 0; f < 4; ++f) {
                int rowA = wm * 64 + f * 16 + (lane & 15);
                int lA = rowA * 128 + ks * 64 + ((lane >> 4) << 4);
                int pA = lA ^ ((rowA & 7) << 4);
                af[f] = *(const bf16x8*)((const char*)smA + pA);
                int rowB = wn * 64 + f * 16 + (lane & 15);
                int lB = rowB * 128 + ks * 64 + ((lane >> 4) << 4);
                int pB = lB ^ ((rowB & 7) << 4);
                bfv[f] = *(const bf16x8*)((const char*)smB + pB);
            }
            #pragma unroll
            for (int i = 0; i < 4; ++i)
                #pragma unroll
                for (int j = 0; j < 4; ++j)
                    acc[i][j] = __builtin_amdgcn_mfma_f32_16x16x32_bf16(
                        af[i], bfv[j], acc[i][j], 0, 0, 0);
        }
        __syncthreads();   // LDS reads done before next stage overwrites
    }

    // Epilogue. C/D layout: col = lane&15, row = (lane>>4)*4 + reg.
    #pragma unroll
    for (int i = 0; i < 4; ++i) {
        #pragma unroll
        for (int j = 0; j < 4; ++j) {
            f32x4 a4 = acc[i][j];
            int gn = n0 + wn * 64 + j * 16 + (lane & 15);
            #pragma unroll
            for (int r = 0; r < 4; ++r) {
                int gm = m0 + wm * 64 + i * 16 + ((lane >> 4) << 2) + r;
                float v = a4[r];
                if (epi == 0) {
                    if (gn < DI_) {
                        u0o[(size_t)gm * DI_ + gn] = v;
                    } else {
                        float sv = v / (1.f + __expf(-v));
                        zso[(size_t)gm * DI_ + (gn - DI_)] = __float2bfloat16(sv);
                    }
                } else if (epi == 1) {
                    outF[(size_t)gm * DM_ + gn] = xres[(size_t)gm * DM_ + gn] + 0.5f * v;
                } else {
                    int gr = (gm & ~(L_ - 1)) | ((L_ - 1) - (gm & (L_ - 1)));
                    outF[(size_t)gr * DM_ + gn] += 0.5f * v;
                }
            }
        }
    }
}

// ---------------- fp32 tiled GEMM (small: xproj, dt) ----------------
#define TM 64
#define TN 64
#define TK 16
#define EPI_NONE     0
#define EPI_SOFTPLUS 1
__global__ __launch_bounds__(256)
void gemm_kernel(const float* __restrict__ A, int lda,
                 const float* __restrict__ W, int ldw,
                 float* __restrict__ C, int ldc,
                 const float* __restrict__ bias,
                 int M, int N, int K, int epi)
{
    __shared__ float sA[TK][TM + 1];
    __shared__ float sW[TK][TN + 1];
    int t  = threadIdx.x;
    int tx = t & 15, ty = t >> 4;
    int m0 = blockIdx.y * TM, n0 = blockIdx.x * TN;
    float acc[4][4] = {};
    for (int k0 = 0; k0 < K; k0 += TK) {
        #pragma unroll
        for (int p = 0; p < 4; ++p) {
            int e = t + p * 256;
            int kk = e & 15, rr = e >> 4;
            int gr = m0 + rr, gk = k0 + kk;
            sA[kk][rr] = (gr < M && gk < K) ? A[(size_t)gr * lda + gk] : 0.f;
        }
        #pragma unroll
        for (int p = 0; p < 4; ++p) {
            int e = t + p * 256;
            int kk = e & 15, rr = e >> 4;
            int gn = n0 + rr, gk = k0 + kk;
            sW[kk][rr] = (gn < N && gk < K) ? W[(size_t)gn * ldw + gk] : 0.f;
        }
        __syncthreads();
        #pragma unroll
        for (int k = 0; k < TK; ++k) {
            float a[4], w[4];
            #pragma unroll
            for (int i = 0; i < 4; ++i) a[i] = sA[k][ty * 4 + i];
            #pragma unroll
            for (int j = 0; j < 4; ++j) w[j] = sW[k][tx * 4 + j];
            #pragma unroll
            for (int i = 0; i < 4; ++i)
                #pragma unroll
                for (int j = 0; j < 4; ++j)
                    acc[i][j] = fmaf(a[i], w[j], acc[i][j]);
        }
        __syncthreads();
    }
    #pragma unroll
    for (int i = 0; i < 4; ++i) {
        int gm = m0 + ty * 4 + i;
        if (gm >= M) continue;
        #pragma unroll
        for (int j = 0; j < 4; ++j) {
            int gn = n0 + tx * 4 + j;
            if (gn >= N) continue;
            float v = acc[i][j];
            if (epi == EPI_NONE) {
                C[(size_t)gm * ldc + gn] = v;
            } else { // softplus
                v += bias[gn];
                C[(size_t)gm * ldc + gn] = (v > 20.f) ? v : log1pf(__expf(v));
            }
        }
    }
}

// ---------------- Causal depthwise conv (width 4) + bias + SiLU ----------------
__global__ __launch_bounds__(256)
void conv_kernel(const float* __restrict__ u0,
                 const float* __restrict__ cw,
                 const float* __restrict__ cb,
                 float* __restrict__ u)
{
    int e = blockIdx.x * 256 + threadIdx.x;   // B*L*DI
    int d = e & (DI_ - 1);
    int l = (e >> 11) & (L_ - 1);
    int b = e >> 22;
    float4 wv = ((const float4*)cw)[d];
    float acc = cb[d];
    size_t base = ((size_t)b * L_) * DI_ + d;
    if (l >= 3) acc += wv.x * u0[base + (size_t)(l - 3) * DI_];
    if (l >= 2) acc += wv.y * u0[base + (size_t)(l - 2) * DI_];
    if (l >= 1) acc += wv.z * u0[base + (size_t)(l - 1) * DI_];
    acc += wv.w * u0[base + (size_t)l * DI_];
    u[e] = acc / (1.f + __expf(-acc));   // silu
}

// ---------------- Selective scan ----------------
#define CHUNK 64
__global__ __launch_bounds__(256)
void scan_kernel(const float* __restrict__ dtb,
                 const float* __restrict__ u,
                 const __hip_bfloat16* __restrict__ zs,   // silu(z), bf16
                 const float* __restrict__ dbc,
                 const float* __restrict__ A_log,
                 const float* __restrict__ Dskip,
                 __hip_bfloat16* __restrict__ yb)
{
    __shared__ float sdt[CHUNK][16], su[CHUNK][16], sz[CHUNK][16];
    __shared__ float sB[CHUNK][16], sC[CHUNK][16], sy[CHUNK][16];
    int t = threadIdx.x;
    int s = t & 15, dloc = t >> 4;
    int d0 = blockIdx.x * 16;
    int b  = blockIdx.y;
    int d  = d0 + dloc;
    float A_ds = -__expf(A_log[d * DS_ + s]);
    float Dd   = Dskip[d];
    float h = 0.f;
    size_t rowbase = (size_t)b * L_;
    for (int l0 = 0; l0 < L_; l0 += CHUNK) {
        #pragma unroll
        for (int p = 0; p < 4; ++p) {
            int e = t + p * 256;
            int ll = e >> 4, dd = e & 15;
            size_t r = rowbase + l0 + ll;
            sdt[ll][dd] = dtb[r * DI_ + d0 + dd];
            su[ll][dd]  = u[r * DI_ + d0 + dd];
            sz[ll][dd]  = __bfloat162float(zs[r * DI_ + d0 + dd]);
            sB[ll][dd]  = dbc[r * NDBC_ + DTR_ + dd];
            sC[ll][dd]  = dbc[r * NDBC_ + DTR_ + DS_ + dd];
        }
        __syncthreads();
        for (int l = 0; l < CHUNK; ++l) {
            float dt = sdt[l][dloc];
            float uu = su[l][dloc];
            float Bt = sB[l][s];
            float Ct = sC[l][s];
            float dA = __expf(dt * A_ds);
            h = dA * h + (dt * uu) * Bt;
            float py = h * Ct;
            py += __shfl_xor(py, 1, 16);
            py += __shfl_xor(py, 2, 16);
            py += __shfl_xor(py, 4, 16);
            py += __shfl_xor(py, 8, 16);
            if (s == 0) sy[l][dloc] = (py + Dd * uu) * sz[l][dloc];
        }
        __syncthreads();
        #pragma unroll
        for (int p = 0; p < 4; ++p) {
            int e = t + p * 256;
            int ll = e >> 4, dd = e & 15;
            size_t r = rowbase + l0 + ll;
            yb[r * DI_ + d0 + dd] = __float2bfloat16(sy[ll][dd]);
        }
    }
}

extern "C" void kernel_launch(void* const* d_in, const int* in_sizes, int n_in,
                              void* d_out, int out_size, void* d_ws, size_t ws_size,
                              hipStream_t stream)
{
    (void)in_sizes; (void)n_in; (void)out_size; (void)ws_size;
    const float* x     = (const float*)d_in[0];
    const float* gamma = (const float*)d_in[1];
    const float* beta  = (const float*)d_in[2];
    float* out = (float*)d_out;

    // workspace layout (~152.5 MB)
    const size_t BLDI = (size_t)B_ * L_ * DI_;
    float* ws  = (float*)d_ws;
    float* u0  = ws;                    // 8.39M f32 (pre-conv activations)
    float* u   = u0 + BLDI;             // 8.39M f32 (post conv+silu)
    float* dt  = u + BLDI;              // 8.39M f32
    float* dbc = dt + BLDI;             // 0.39M f32
    __hip_bfloat16* lnb = (__hip_bfloat16*)(dbc + (size_t)B_ * L_ * NDBC_);
    __hip_bfloat16* zs  = lnb + (size_t)B_ * L_ * DM_;   // silu(z), bf16
    __hip_bfloat16* yb  = zs + BLDI;                     // scan out, bf16
    __hip_bfloat16* wb  = yb + BLDI;                     // bf16 weights (reused)

    dim3 blk(256);
    ln_kernel<<<B_ * L_, blk, 0, stream>>>(x, gamma, beta, lnb);

    for (int dir = 0; dir < 2; ++dir) {
        int base = 3 + dir * 9;
        const float* in_w    = (const float*)d_in[base + 0];
        const float* conv_w  = (const float*)d_in[base + 1];
        const float* conv_b  = (const float*)d_in[base + 2];
        const float* xproj_w = (const float*)d_in[base + 3];
        const float* dt_w    = (const float*)d_in[base + 4];
        const float* dt_b    = (const float*)d_in[base + 5];
        const float* A_log   = (const float*)d_in[base + 6];
        const float* Dsk     = (const float*)d_in[base + 7];
        const float* out_w   = (const float*)d_in[base + 8];

        // in_w -> bf16
        cvt_kernel<<<(NXZ_ * DM_) / 1024, blk, 0, stream>>>(in_w, wb, NXZ_ * DM_);

        // in_proj: [u0 | silu(z)] = ln(flip?) @ in_w^T  (M=4096,N=4096,K=1024)
        mfma_gemm<<<dim3(NXZ_ / GBM, (B_ * L_) / GBM), blk, 0, stream>>>(
            lnb, DM_, wb, DM_, DM_, dir, 0, nullptr, nullptr, u0, zs);

        // causal depthwise conv + silu -> u
        conv_kernel<<<(B_ * L_ * DI_) / 256, blk, 0, stream>>>(u0, conv_w, conv_b, u);

        // xproj: dbc = u @ xproj_w^T   (M=4096, N=96, K=2048)
        gemm_kernel<<<dim3((NDBC_ + TN - 1) / TN, (B_ * L_) / TM), blk, 0, stream>>>(
            u, DI_, xproj_w, DI_, dbc, NDBC_, nullptr,
            B_ * L_, NDBC_, DI_, EPI_NONE);

        // dt = softplus(dbc[:, :64] @ dt_w^T + dt_b)  (M=4096, N=2048, K=64)
        gemm_kernel<<<dim3(DI_ / TN, (B_ * L_) / TM), blk, 0, stream>>>(
            dbc, NDBC_, dt_w, DTR_, dt, DI_, dt_b,
            B_ * L_, DI_, DTR_, EPI_SOFTPLUS);

        // selective scan -> yb (bf16), fused D-skip + silu(z) gate
        scan_kernel<<<dim3(DI_ / 16, B_), blk, 0, stream>>>(
            dt, u, zs, dbc, A_log, Dsk, yb);

        // out_w -> bf16
        cvt_kernel<<<(DM_ * DI_) / 1024, blk, 0, stream>>>(out_w, wb, DM_ * DI_);

        // out_proj + residual combine  (M=4096, N=1024, K=2048)
        mfma_gemm<<<dim3(DM_ / GBM, (B_ * L_) / GBM), blk, 0, stream>>>(
            yb, DI_, wb, DI_, DI_, 0, dir ? 2 : 1, x, out, nullptr, nullptr);
    }
}

// Round 3
// 1100.570 us; speedup vs baseline: 3.8396x; 1.7597x over previous
//
#include <hip/hip_runtime.h>
#include <hip/hip_bf16.h>
#include <math.h>

// Problem constants
#define B_    2
#define L_    2048
#define DM_   1024      // d_model
#define DI_   2048      // d_inner
#define DS_   16        // d_state
#define DTR_  64        // dt_rank
#define NXZ_  4096      // 2*d_inner
#define NDBC_ 96        // dt_rank + 2*d_state

#define NSEG   32
#define SEGLEN 64
#define SCHUNK 32

typedef __attribute__((ext_vector_type(8))) short bf16x8;
typedef __attribute__((ext_vector_type(4))) float f32x4;

__device__ __forceinline__ void gload_lds16(const void* g, void* l) {
    __builtin_amdgcn_global_load_lds(
        (const __attribute__((address_space(1))) void*)g,
        (__attribute__((address_space(3))) void*)l,
        16, 0, 0);
}

// ---------------- LayerNorm (one block per row) -> bf16 out ----------------
__global__ __launch_bounds__(256)
void ln_kernel(const float* __restrict__ x,
               const float* __restrict__ gamma,
               const float* __restrict__ beta,
               __hip_bfloat16* __restrict__ out)
{
    int row = blockIdx.x;
    int t = threadIdx.x;
    const float* xr = x + (size_t)row * DM_;
    float4 v = ((const float4*)xr)[t];
    float s  = v.x + v.y + v.z + v.w;
    float ss = v.x*v.x + v.y*v.y + v.z*v.z + v.w*v.w;
    #pragma unroll
    for (int m = 1; m < 64; m <<= 1) {
        s  += __shfl_xor(s,  m, 64);
        ss += __shfl_xor(ss, m, 64);
    }
    __shared__ float as_[4], ass_[4];
    int w = t >> 6;
    if ((t & 63) == 0) { as_[w] = s; ass_[w] = ss; }
    __syncthreads();
    s  = as_[0] + as_[1] + as_[2] + as_[3];
    ss = ass_[0] + ass_[1] + ass_[2] + ass_[3];
    float mu  = s * (1.0f / DM_);
    float var = ss * (1.0f / DM_) - mu * mu;
    float inv = rsqrtf(var + 1e-5f);
    float4 g  = ((const float4*)gamma)[t];
    float4 bt = ((const float4*)beta)[t];
    __hip_bfloat16 ob[4];
    ob[0] = __float2bfloat16((v.x - mu) * inv * g.x + bt.x);
    ob[1] = __float2bfloat16((v.y - mu) * inv * g.y + bt.y);
    ob[2] = __float2bfloat16((v.z - mu) * inv * g.z + bt.z);
    ob[3] = __float2bfloat16((v.w - mu) * inv * g.w + bt.w);
    ((ushort4*)(out + (size_t)row * DM_))[t] = *(const ushort4*)ob;
}

// ---------------- fp32 -> bf16 convert ----------------
__global__ __launch_bounds__(256)
void cvt_kernel(const float* __restrict__ s, __hip_bfloat16* __restrict__ d, int n)
{
    int i = (blockIdx.x * 256 + threadIdx.x) * 4;
    if (i >= n) return;
    float4 v = *(const float4*)(s + i);
    __hip_bfloat16 ob[4];
    ob[0] = __float2bfloat16(v.x);
    ob[1] = __float2bfloat16(v.y);
    ob[2] = __float2bfloat16(v.z);
    ob[3] = __float2bfloat16(v.w);
    *(ushort4*)(d + i) = *(const ushort4*)ob;
}

// ---------------- bf16 MFMA GEMM: C = A(MxK) @ W(NxK)^T ----------------
// 128x128 tile, BK=64, global_load_lds + XOR swizzle (both-sides).
// epi: 0=in_proj split, 1=out_fw, 2=out_bw, 3=xproj, 4=dt softplus
#define GBM 128
#define GBK 64
__global__ __launch_bounds__(256)
void mfma_gemm(const __hip_bfloat16* __restrict__ A, int lda,
               const __hip_bfloat16* __restrict__ W, int ldw,
               int K, int Nw, int flipA, int epi,
               const float* __restrict__ aux,
               float* __restrict__ out0,
               __hip_bfloat16* __restrict__ ob1,
               __hip_bfloat16* __restrict__ ob2)
{
    __shared__ __hip_bfloat16 smA[GBM * GBK];   // 16 KB
    __shared__ __hip_bfloat16 smB[GBM * GBK];   // 16 KB
    int t = threadIdx.x;
    int lane = t & 63, wid = t >> 6;
    int wm = wid >> 1, wn = wid & 1;
    int m0 = blockIdx.y * GBM, n0 = blockIdx.x * GBM;

    f32x4 acc[4][4];
    #pragma unroll
    for (int i = 0; i < 4; ++i)
        #pragma unroll
        for (int j = 0; j < 4; ++j)
            acc[i][j] = (f32x4){0.f, 0.f, 0.f, 0.f};

    int arows[4], brows[4], cbs[4];
    #pragma unroll
    for (int p = 0; p < 4; ++p) {
        int o = p * 4096 + t * 16;
        int l = o ^ (((o >> 7) & 7) << 4);
        int r = l >> 7, cb = l & 127;
        int gr = m0 + r;
        if (flipA) gr = (gr & ~(L_ - 1)) | ((L_ - 1) - (gr & (L_ - 1)));
        arows[p] = gr;
        int wr = n0 + r; if (wr >= Nw) wr = Nw - 1;   // clamp (N=96 case)
        brows[p] = wr;
        cbs[p] = cb;
    }

    for (int k0 = 0; k0 < K; k0 += GBK) {
        #pragma unroll
        for (int p = 0; p < 4; ++p) {
            int o = p * 4096 + t * 16;
            const char* gA = (const char*)(A + (size_t)arows[p] * lda + k0) + cbs[p];
            gload_lds16(gA, (char*)smA + o);
            const char* gB = (const char*)(W + (size_t)brows[p] * ldw + k0) + cbs[p];
            gload_lds16(gB, (char*)smB + o);
        }
        __syncthreads();

        #pragma unroll
        for (int ks = 0; ks < 2; ++ks) {
            bf16x8 af[4], bfv[4];
            #pragma unroll
            for (int f = 0; f < 4; ++f) {
                int rowA = wm * 64 + f * 16 + (lane & 15);
                int lA = rowA * 128 + ks * 64 + ((lane >> 4) << 4);
                int pA = lA ^ ((rowA & 7) << 4);
                af[f] = *(const bf16x8*)((const char*)smA + pA);
                int rowB = wn * 64 + f * 16 + (lane & 15);
                int lB = rowB * 128 + ks * 64 + ((lane >> 4) << 4);
                int pB = lB ^ ((rowB & 7) << 4);
                bfv[f] = *(const bf16x8*)((const char*)smB + pB);
            }
            #pragma unroll
            for (int i = 0; i < 4; ++i)
                #pragma unroll
                for (int j = 0; j < 4; ++j)
                    acc[i][j] = __builtin_amdgcn_mfma_f32_16x16x32_bf16(
                        af[i], bfv[j], acc[i][j], 0, 0, 0);
        }
        __syncthreads();
    }

    // Epilogue. C/D layout: col = lane&15, row = (lane>>4)*4 + reg.
    #pragma unroll
    for (int i = 0; i < 4; ++i) {
        #pragma unroll
        for (int j = 0; j < 4; ++j) {
            f32x4 a4 = acc[i][j];
            int gn = n0 + wn * 64 + j * 16 + (lane & 15);
            #pragma unroll
            for (int r = 0; r < 4; ++r) {
                int gm = m0 + wm * 64 + i * 16 + ((lane >> 4) << 2) + r;
                float v = a4[r];
                if (epi == 0) {
                    if (gn < DI_) {
                        ob1[(size_t)gm * DI_ + gn] = __float2bfloat16(v);
                    } else {
                        float sv = v / (1.f + __expf(-v));
                        ob2[(size_t)gm * DI_ + (gn - DI_)] = __float2bfloat16(sv);
                    }
                } else if (epi == 1) {
                    out0[(size_t)gm * DM_ + gn] = aux[(size_t)gm * DM_ + gn] + 0.5f * v;
                } else if (epi == 2) {
                    int gr = (gm & ~(L_ - 1)) | ((L_ - 1) - (gm & (L_ - 1)));
                    out0[(size_t)gr * DM_ + gn] += 0.5f * v;
                } else if (epi == 3) {
                    if (gn < NDBC_) out0[(size_t)gm * NDBC_ + gn] = v;
                    if (gn < DTR_)  ob1[(size_t)gm * DTR_ + gn] = __float2bfloat16(v);
                } else { // epi == 4: dt softplus
                    if (gn < DI_) {
                        v += aux[gn];
                        out0[(size_t)gm * DI_ + gn] = (v > 20.f) ? v : log1pf(__expf(v));
                    }
                }
            }
        }
    }
}

// ---------------- Causal depthwise conv (width 4) + bias + SiLU ----------------
__global__ __launch_bounds__(256)
void conv_kernel(const __hip_bfloat16* __restrict__ u0,
                 const float* __restrict__ cw,
                 const float* __restrict__ cb,
                 __hip_bfloat16* __restrict__ u)
{
    int e = blockIdx.x * 256 + threadIdx.x;   // B*L*DI
    int d = e & (DI_ - 1);
    int l = (e >> 11) & (L_ - 1);
    size_t base = (size_t)(e - (l << 11) - d) + d;   // == (b*L)*DI + d
    float4 wv = ((const float4*)cw)[d];
    float acc = cb[d];
    if (l >= 3) acc += wv.x * __bfloat162float(u0[base + (size_t)(l - 3) * DI_]);
    if (l >= 2) acc += wv.y * __bfloat162float(u0[base + (size_t)(l - 2) * DI_]);
    if (l >= 1) acc += wv.z * __bfloat162float(u0[base + (size_t)(l - 1) * DI_]);
    acc += wv.w * __bfloat162float(u0[base + (size_t)l * DI_]);
    u[e] = __float2bfloat16(acc / (1.f + __expf(-acc)));   // silu
}

// ---------------- Segmented selective scan ----------------
// Pass 1: per-segment local scan from h=0; store final h + sum(dt) per (d).
__global__ __launch_bounds__(256)
void scan_part1(const float* __restrict__ dtb,
                const __hip_bfloat16* __restrict__ ub,
                const float* __restrict__ dbcF,
                const float* __restrict__ A_log,
                float* __restrict__ hseg,
                float* __restrict__ dtsum)
{
    __shared__ float sdt[SCHUNK][16], su[SCHUNK][16], sB[SCHUNK][16];
    int t = threadIdx.x;
    int s = t & 15, dloc = t >> 4;
    int d0 = blockIdx.x * 16, seg = blockIdx.y, b = blockIdx.z;
    int d = d0 + dloc;
    float A_ds = -__expf(A_log[d * DS_ + s]);
    float h = 0.f, dts = 0.f;
    size_t rowbase = (size_t)b * L_ + seg * SEGLEN;
    for (int c = 0; c < SEGLEN / SCHUNK; ++c) {
        #pragma unroll
        for (int p = 0; p < 2; ++p) {
            int e = t + p * 256;
            int ll = e >> 4, dd = e & 15;
            size_t r = rowbase + c * SCHUNK + ll;
            sdt[ll][dd] = dtb[r * DI_ + d0 + dd];
            su[ll][dd]  = __bfloat162float(ub[r * DI_ + d0 + dd]);
            sB[ll][dd]  = dbcF[r * NDBC_ + DTR_ + dd];
        }
        __syncthreads();
        #pragma unroll 4
        for (int l = 0; l < SCHUNK; ++l) {
            float dtv = sdt[l][dloc];
            float uu  = su[l][dloc];
            float Bt  = sB[l][s];
            h = __expf(dtv * A_ds) * h + (dtv * uu) * Bt;
            dts += dtv;
        }
        __syncthreads();
    }
    size_t o = (((size_t)b * NSEG + seg) * DI_ + d) * DS_ + s;
    hseg[o] = h;
    if (s == 0) dtsum[((size_t)b * NSEG + seg) * DI_ + d] = dts;
}

// Pass 2: inter-segment scan, in place (hseg becomes h_in per segment).
__global__ __launch_bounds__(256)
void seg_scan(float* __restrict__ hseg,
              const float* __restrict__ dtsum,
              const float* __restrict__ A_log)
{
    int idx = blockIdx.x * 256 + threadIdx.x;   // (b, d, s)
    int s = idx & 15;
    int d = (idx >> 4) & (DI_ - 1);
    int b = idx >> 15;
    float A_ds = -__expf(A_log[d * DS_ + s]);
    float h = 0.f;
    for (int g = 0; g < NSEG; ++g) {
        size_t o = (((size_t)b * NSEG + g) * DI_ + d) * DS_ + s;
        float prev = hseg[o];
        hseg[o] = h;
        h = __expf(A_ds * dtsum[((size_t)b * NSEG + g) * DI_ + d]) * h + prev;
    }
}

// Pass 3: re-scan with correct h_in; write y (fused D-skip + silu(z) gate).
__global__ __launch_bounds__(256)
void scan_part2(const float* __restrict__ dtb,
                const __hip_bfloat16* __restrict__ ub,
                const __hip_bfloat16* __restrict__ zs,
                const float* __restrict__ dbcF,
                const float* __restrict__ A_log,
                const float* __restrict__ Dskip,
                const float* __restrict__ hseg,
                __hip_bfloat16* __restrict__ yb)
{
    __shared__ float sdt[SCHUNK][16], su[SCHUNK][16], sz[SCHUNK][16];
    __shared__ float sB[SCHUNK][16], sC[SCHUNK][16], sy[SCHUNK][16];
    int t = threadIdx.x;
    int s = t & 15, dloc = t >> 4;
    int d0 = blockIdx.x * 16, seg = blockIdx.y, b = blockIdx.z;
    int d = d0 + dloc;
    float A_ds = -__expf(A_log[d * DS_ + s]);
    float Dd   = Dskip[d];
    float h = hseg[(((size_t)b * NSEG + seg) * DI_ + d) * DS_ + s];
    size_t rowbase = (size_t)b * L_ + seg * SEGLEN;
    for (int c = 0; c < SEGLEN / SCHUNK; ++c) {
        #pragma unroll
        for (int p = 0; p < 2; ++p) {
            int e = t + p * 256;
            int ll = e >> 4, dd = e & 15;
            size_t r = rowbase + c * SCHUNK + ll;
            sdt[ll][dd] = dtb[r * DI_ + d0 + dd];
            su[ll][dd]  = __bfloat162float(ub[r * DI_ + d0 + dd]);
            sz[ll][dd]  = __bfloat162float(zs[r * DI_ + d0 + dd]);
            sB[ll][dd]  = dbcF[r * NDBC_ + DTR_ + dd];
            sC[ll][dd]  = dbcF[r * NDBC_ + DTR_ + DS_ + dd];
        }
        __syncthreads();
        for (int l = 0; l < SCHUNK; ++l) {
            float dtv = sdt[l][dloc];
            float uu  = su[l][dloc];
            float Bt  = sB[l][s];
            float Ct  = sC[l][s];
            h = __expf(dtv * A_ds) * h + (dtv * uu) * Bt;
            float py = h * Ct;
            py += __shfl_xor(py, 1, 16);
            py += __shfl_xor(py, 2, 16);
            py += __shfl_xor(py, 4, 16);
            py += __shfl_xor(py, 8, 16);
            if (s == 0) sy[l][dloc] = (py + Dd * uu) * sz[l][dloc];
        }
        __syncthreads();
        #pragma unroll
        for (int p = 0; p < 2; ++p) {
            int e = t + p * 256;
            int ll = e >> 4, dd = e & 15;
            size_t r = rowbase + c * SCHUNK + ll;
            yb[r * DI_ + d0 + dd] = __float2bfloat16(sy[ll][dd]);
        }
    }
}

extern "C" void kernel_launch(void* const* d_in, const int* in_sizes, int n_in,
                              void* d_out, int out_size, void* d_ws, size_t ws_size,
                              hipStream_t stream)
{
    (void)in_sizes; (void)n_in; (void)out_size; (void)ws_size;
    const float* x     = (const float*)d_in[0];
    const float* gamma = (const float*)d_in[1];
    const float* beta  = (const float*)d_in[2];
    float* out = (float*)d_out;

    const size_t BLDI = (size_t)B_ * L_ * DI_;      // 8,388,608
    float* ws    = (float*)d_ws;
    float* dt    = ws;                               // 33.55 MB
    float* dbcF  = dt + BLDI;                        // 1.57 MB
    float* dtsum = dbcF + (size_t)B_ * L_ * NDBC_;   // 0.52 MB
    float* hseg  = dtsum + (size_t)B_ * NSEG * DI_;  // 8.39 MB
    __hip_bfloat16* lnb  = (__hip_bfloat16*)(hseg + (size_t)B_ * NSEG * DI_ * DS_);
    __hip_bfloat16* u0b  = lnb + (size_t)B_ * L_ * DM_;
    __hip_bfloat16* ub   = u0b + BLDI;
    __hip_bfloat16* zs   = ub + BLDI;
    __hip_bfloat16* yb   = zs + BLDI;
    __hip_bfloat16* wb   = yb + BLDI;                // in_w / out_w (reused)
    __hip_bfloat16* xpwb = wb + (size_t)NXZ_ * DM_;
    __hip_bfloat16* dtwb = xpwb + (size_t)NDBC_ * DI_;
    __hip_bfloat16* dbcB = dtwb + (size_t)DI_ * DTR_;

    dim3 blk(256);
    ln_kernel<<<B_ * L_, blk, 0, stream>>>(x, gamma, beta, lnb);

    for (int dir = 0; dir < 2; ++dir) {
        int base = 3 + dir * 9;
        const float* in_w    = (const float*)d_in[base + 0];
        const float* conv_w  = (const float*)d_in[base + 1];
        const float* conv_b  = (const float*)d_in[base + 2];
        const float* xproj_w = (const float*)d_in[base + 3];
        const float* dt_w    = (const float*)d_in[base + 4];
        const float* dt_b    = (const float*)d_in[base + 5];
        const float* A_log   = (const float*)d_in[base + 6];
        const float* Dsk     = (const float*)d_in[base + 7];
        const float* out_w   = (const float*)d_in[base + 8];

        cvt_kernel<<<(NXZ_ * DM_) / 1024, blk, 0, stream>>>(in_w, wb, NXZ_ * DM_);
        // in_proj: [u0b | silu(z)->zs] = ln(flip?) @ in_w^T
        mfma_gemm<<<dim3(NXZ_ / GBM, (B_ * L_) / GBM), blk, 0, stream>>>(
            lnb, DM_, wb, DM_, DM_, NXZ_, dir, 0, nullptr, nullptr, u0b, zs);

        conv_kernel<<<(B_ * L_ * DI_) / 256, blk, 0, stream>>>(u0b, conv_w, conv_b, ub);

        cvt_kernel<<<(NDBC_ * DI_) / 1024, blk, 0, stream>>>(xproj_w, xpwb, NDBC_ * DI_);
        // xproj: dbc = u @ xproj_w^T (N=96, clamped tile)
        mfma_gemm<<<dim3(1, (B_ * L_) / GBM), blk, 0, stream>>>(
            ub, DI_, xpwb, DI_, DI_, NDBC_, 0, 3, nullptr, dbcF, dbcB, nullptr);

        cvt_kernel<<<(DI_ * DTR_) / 1024, blk, 0, stream>>>(dt_w, dtwb, DI_ * DTR_);
        // dt = softplus(dbc[:, :64] @ dt_w^T + dt_b)
        mfma_gemm<<<dim3(DI_ / GBM, (B_ * L_) / GBM), blk, 0, stream>>>(
            dbcB, DTR_, dtwb, DTR_, DTR_, DI_, 0, 4, dt_b, dt, nullptr, nullptr);

        // segmented scan
        scan_part1<<<dim3(DI_ / 16, NSEG, B_), blk, 0, stream>>>(
            dt, ub, dbcF, A_log, hseg, dtsum);
        seg_scan<<<(B_ * DI_ * DS_) / 256, blk, 0, stream>>>(hseg, dtsum, A_log);
        scan_part2<<<dim3(DI_ / 16, NSEG, B_), blk, 0, stream>>>(
            dt, ub, zs, dbcF, A_log, Dsk, hseg, yb);

        cvt_kernel<<<(DM_ * DI_) / 1024, blk, 0, stream>>>(out_w, wb, DM_ * DI_);
        // out_proj + residual combine
        mfma_gemm<<<dim3(DM_ / GBM, (B_ * L_) / GBM), blk, 0, stream>>>(
            yb, DI_, wb, DI_, DI_, DM_, 0, dir ? 2 : 1, x, out, nullptr, nullptr);
    }
}

// Round 4
// 933.664 us; speedup vs baseline: 4.5259x; 1.1788x over previous
//
#include <hip/hip_runtime.h>
#include <hip/hip_bf16.h>
#include <math.h>

// Problem constants
#define B_    2
#define L_    2048
#define DM_   1024      // d_model
#define DI_   2048      // d_inner
#define DS_   16        // d_state
#define DTR_  64        // dt_rank
#define NXZ_  4096      // 2*d_inner
#define NDBC_ 96        // dt_rank + 2*d_state

#define NSEG   64
#define SEGLEN 32
#define CT     16       // timesteps staged per chunk
#define KS_    8        // xproj split-K factor

#define LOG2E 1.4426950408889634f

typedef __attribute__((ext_vector_type(8))) short bf16x8;
typedef __attribute__((ext_vector_type(4))) float f32x4;

__device__ __forceinline__ void gload_lds16(const void* g, void* l) {
    __builtin_amdgcn_global_load_lds(
        (const __attribute__((address_space(1))) void*)g,
        (__attribute__((address_space(3))) void*)l,
        16, 0, 0);
}

// ---------------- LayerNorm (one block per row) -> bf16 out ----------------
__global__ __launch_bounds__(256)
void ln_kernel(const float* __restrict__ x,
               const float* __restrict__ gamma,
               const float* __restrict__ beta,
               __hip_bfloat16* __restrict__ out)
{
    int row = blockIdx.x;
    int t = threadIdx.x;
    const float* xr = x + (size_t)row * DM_;
    float4 v = ((const float4*)xr)[t];
    float s  = v.x + v.y + v.z + v.w;
    float ss = v.x*v.x + v.y*v.y + v.z*v.z + v.w*v.w;
    #pragma unroll
    for (int m = 1; m < 64; m <<= 1) {
        s  += __shfl_xor(s,  m, 64);
        ss += __shfl_xor(ss, m, 64);
    }
    __shared__ float as_[4], ass_[4];
    int w = t >> 6;
    if ((t & 63) == 0) { as_[w] = s; ass_[w] = ss; }
    __syncthreads();
    s  = as_[0] + as_[1] + as_[2] + as_[3];
    ss = ass_[0] + ass_[1] + ass_[2] + ass_[3];
    float mu  = s * (1.0f / DM_);
    float var = ss * (1.0f / DM_) - mu * mu;
    float inv = rsqrtf(var + 1e-5f);
    float4 g  = ((const float4*)gamma)[t];
    float4 bt = ((const float4*)beta)[t];
    __hip_bfloat16 ob[4];
    ob[0] = __float2bfloat16((v.x - mu) * inv * g.x + bt.x);
    ob[1] = __float2bfloat16((v.y - mu) * inv * g.y + bt.y);
    ob[2] = __float2bfloat16((v.z - mu) * inv * g.z + bt.z);
    ob[3] = __float2bfloat16((v.w - mu) * inv * g.w + bt.w);
    ((ushort4*)(out + (size_t)row * DM_))[t] = *(const ushort4*)ob;
}

// ---------------- fp32 -> bf16 convert ----------------
__global__ __launch_bounds__(256)
void cvt_kernel(const float* __restrict__ s, __hip_bfloat16* __restrict__ d, int n)
{
    int i = (blockIdx.x * 256 + threadIdx.x) * 4;
    if (i >= n) return;
    float4 v = *(const float4*)(s + i);
    __hip_bfloat16 ob[4];
    ob[0] = __float2bfloat16(v.x);
    ob[1] = __float2bfloat16(v.y);
    ob[2] = __float2bfloat16(v.z);
    ob[3] = __float2bfloat16(v.w);
    *(ushort4*)(d + i) = *(const ushort4*)ob;
}

// ---------------- bf16 MFMA GEMM: C = A(MxK) @ W(NxK)^T ----------------
// 128x128 tile, BK=64, global_load_lds + XOR swizzle (both-sides).
// epi: 0=in_proj split, 1=out_fw, 2=out_bw, 3=xproj split-K partial, 4=dt softplus
#define GBM 128
#define GBK 64
__global__ __launch_bounds__(256)
void mfma_gemm(const __hip_bfloat16* __restrict__ A, int lda,
               const __hip_bfloat16* __restrict__ W, int ldw,
               int K, int Kslice, int Nw, int flipA, int epi,
               const float* __restrict__ aux,
               float* __restrict__ out0,
               __hip_bfloat16* __restrict__ ob1,
               __hip_bfloat16* __restrict__ ob2)
{
    __shared__ __hip_bfloat16 smA[GBM * GBK];   // 16 KB
    __shared__ __hip_bfloat16 smB[GBM * GBK];   // 16 KB
    int t = threadIdx.x;
    int lane = t & 63, wid = t >> 6;
    int wm = wid >> 1, wn = wid & 1;
    int m0 = blockIdx.y * GBM, n0 = blockIdx.x * GBM;
    int kz = blockIdx.z;
    int k_begin = kz * Kslice;
    int k_end   = (k_begin + Kslice < K) ? (k_begin + Kslice) : K;

    f32x4 acc[4][4];
    #pragma unroll
    for (int i = 0; i < 4; ++i)
        #pragma unroll
        for (int j = 0; j < 4; ++j)
            acc[i][j] = (f32x4){0.f, 0.f, 0.f, 0.f};

    int arows[4], brows[4], cbs[4];
    #pragma unroll
    for (int p = 0; p < 4; ++p) {
        int o = p * 4096 + t * 16;
        int l = o ^ (((o >> 7) & 7) << 4);
        int r = l >> 7, cb = l & 127;
        int gr = m0 + r;
        if (flipA) gr = (gr & ~(L_ - 1)) | ((L_ - 1) - (gr & (L_ - 1)));
        arows[p] = gr;
        int wr = n0 + r; if (wr >= Nw) wr = Nw - 1;   // clamp (N=96 case)
        brows[p] = wr;
        cbs[p] = cb;
    }

    for (int k0 = k_begin; k0 < k_end; k0 += GBK) {
        #pragma unroll
        for (int p = 0; p < 4; ++p) {
            int o = p * 4096 + t * 16;
            const char* gA = (const char*)(A + (size_t)arows[p] * lda + k0) + cbs[p];
            gload_lds16(gA, (char*)smA + o);
            const char* gB = (const char*)(W + (size_t)brows[p] * ldw + k0) + cbs[p];
            gload_lds16(gB, (char*)smB + o);
        }
        __syncthreads();

        #pragma unroll
        for (int ks = 0; ks < 2; ++ks) {
            bf16x8 af[4], bfv[4];
            #pragma unroll
            for (int f = 0; f < 4; ++f) {
                int rowA = wm * 64 + f * 16 + (lane & 15);
                int lA = rowA * 128 + ks * 64 + ((lane >> 4) << 4);
                int pA = lA ^ ((rowA & 7) << 4);
                af[f] = *(const bf16x8*)((const char*)smA + pA);
                int rowB = wn * 64 + f * 16 + (lane & 15);
                int lB = rowB * 128 + ks * 64 + ((lane >> 4) << 4);
                int pB = lB ^ ((rowB & 7) << 4);
                bfv[f] = *(const bf16x8*)((const char*)smB + pB);
            }
            #pragma unroll
            for (int i = 0; i < 4; ++i)
                #pragma unroll
                for (int j = 0; j < 4; ++j)
                    acc[i][j] = __builtin_amdgcn_mfma_f32_16x16x32_bf16(
                        af[i], bfv[j], acc[i][j], 0, 0, 0);
        }
        __syncthreads();
    }

    // Epilogue. C/D layout: col = lane&15, row = (lane>>4)*4 + reg.
    #pragma unroll
    for (int i = 0; i < 4; ++i) {
        #pragma unroll
        for (int j = 0; j < 4; ++j) {
            f32x4 a4 = acc[i][j];
            int gn = n0 + wn * 64 + j * 16 + (lane & 15);
            #pragma unroll
            for (int r = 0; r < 4; ++r) {
                int gm = m0 + wm * 64 + i * 16 + ((lane >> 4) << 2) + r;
                float v = a4[r];
                if (epi == 0) {
                    if (gn < DI_) {
                        ob1[(size_t)gm * DI_ + gn] = __float2bfloat16(v);
                    } else {
                        float sv = v / (1.f + __expf(-v));
                        ob2[(size_t)gm * DI_ + (gn - DI_)] = __float2bfloat16(sv);
                    }
                } else if (epi == 1) {
                    out0[(size_t)gm * DM_ + gn] = aux[(size_t)gm * DM_ + gn] + 0.5f * v;
                } else if (epi == 2) {
                    int gr = (gm & ~(L_ - 1)) | ((L_ - 1) - (gm & (L_ - 1)));
                    out0[(size_t)gr * DM_ + gn] += 0.5f * v;
                } else if (epi == 3) {
                    // split-K partial, padded ldc=128 (cols >=96 are garbage)
                    out0[((size_t)kz * (B_ * L_) + gm) * 128 + gn] = v;
                } else { // epi == 4: dt softplus
                    if (gn < DI_) {
                        v += aux[gn];
                        out0[(size_t)gm * DI_ + gn] = (v > 20.f) ? v : log1pf(__expf(v));
                    }
                }
            }
        }
    }
}

// ---------------- xproj split-K reduce ----------------
__global__ __launch_bounds__(256)
void xproj_reduce(const float* __restrict__ pbuf,
                  float* __restrict__ dbcF,
                  __hip_bfloat16* __restrict__ dbcB)
{
    int idx = blockIdx.x * 256 + threadIdx.x;   // (B*L) * 128
    int n = idx & 127, m = idx >> 7;
    float sum = 0.f;
    #pragma unroll
    for (int k = 0; k < KS_; ++k)
        sum += pbuf[((size_t)k * (B_ * L_) + m) * 128 + n];
    if (n < NDBC_) dbcF[(size_t)m * NDBC_ + n] = sum;
    if (n < DTR_)  dbcB[(size_t)m * DTR_ + n] = __float2bfloat16(sum);
}

// ---------------- Causal depthwise conv (width 4) + bias + SiLU ----------------
__global__ __launch_bounds__(256)
void conv_kernel(const __hip_bfloat16* __restrict__ u0,
                 const float* __restrict__ cw,
                 const float* __restrict__ cb,
                 __hip_bfloat16* __restrict__ u)
{
    int e = blockIdx.x * 256 + threadIdx.x;   // B*L*DI
    int d = e & (DI_ - 1);
    int l = (e >> 11) & (L_ - 1);
    size_t base = (size_t)(e - (l << 11) - d) + d;   // == (b*L)*DI + d
    float4 wv = ((const float4*)cw)[d];
    float acc = cb[d];
    if (l >= 3) acc += wv.x * __bfloat162float(u0[base + (size_t)(l - 3) * DI_]);
    if (l >= 2) acc += wv.y * __bfloat162float(u0[base + (size_t)(l - 2) * DI_]);
    if (l >= 1) acc += wv.z * __bfloat162float(u0[base + (size_t)(l - 1) * DI_]);
    acc += wv.w * __bfloat162float(u0[base + (size_t)l * DI_]);
    u[e] = __float2bfloat16(acc / (1.f + __expf(-acc)));   // silu
}

// ---------------- Segmented selective scan: thread-per-channel ----------------
// Thread t owns channel d = blockIdx.x*256 + t; h[16] in registers.
// B_t/C_t are per-(b,l) shared across d -> LDS broadcast. No cross-lane ops.

// Pass 1: per-segment local scan from h=0; store final h + sum(dt).
__global__ __launch_bounds__(256)
void scan_part1(const float* __restrict__ dtb,
                const __hip_bfloat16* __restrict__ ub,
                const float* __restrict__ dbcF,
                const float* __restrict__ A_log,
                float* __restrict__ hseg,     // [b][seg][s][DI]
                float* __restrict__ dtsum)    // [b][seg][DI]
{
    __shared__ float sdt[CT][256];
    __shared__ __hip_bfloat16 su[CT][256];
    __shared__ float sB[CT][DS_];
    int t = threadIdx.x;
    int d0 = blockIdx.x * 256, seg = blockIdx.y, b = blockIdx.z;
    int d = d0 + t;
    float A2[DS_], h[DS_];
    #pragma unroll
    for (int s = 0; s < DS_; ++s) {
        A2[s] = -__expf(A_log[d * DS_ + s]) * LOG2E;
        h[s] = 0.f;
    }
    float dts = 0.f;
    size_t rowbase = (size_t)b * L_ + seg * SEGLEN;
    for (int c = 0; c < SEGLEN / CT; ++c) {
        #pragma unroll
        for (int p = 0; p < CT; ++p) {
            size_t r = rowbase + c * CT + p;
            sdt[p][t] = dtb[r * DI_ + d];
            su[p][t]  = ub[r * DI_ + d];
        }
        {
            int ll = t >> 4, ss = t & 15;   // 256 threads cover CT*16
            sB[ll][ss] = dbcF[(rowbase + c * CT + ll) * NDBC_ + DTR_ + ss];
        }
        __syncthreads();
        for (int l = 0; l < CT; ++l) {
            float dtv = sdt[l][t];
            float du  = dtv * __bfloat162float(su[l][t]);
            dts += dtv;
            #pragma unroll
            for (int s = 0; s < DS_; ++s)
                h[s] = exp2f(dtv * A2[s]) * h[s] + du * sB[l][s];
        }
        __syncthreads();
    }
    #pragma unroll
    for (int s = 0; s < DS_; ++s)
        hseg[(((size_t)b * NSEG + seg) * DS_ + s) * DI_ + d] = h[s];
    dtsum[((size_t)b * NSEG + seg) * DI_ + d] = dts;
}

// Pass 2: inter-segment scan, in place (hseg becomes h_in per segment).
__global__ __launch_bounds__(256)
void seg_scan(float* __restrict__ hseg,
              const float* __restrict__ dtsum,
              const float* __restrict__ A_log)
{
    int idx = blockIdx.x * 256 + threadIdx.x;   // b*DI*DS, d fastest
    int d = idx & (DI_ - 1);
    int s = (idx >> 11) & 15;
    int b = idx >> 15;
    float A2 = -__expf(A_log[d * DS_ + s]) * LOG2E;
    float h = 0.f;
    for (int g = 0; g < NSEG; ++g) {
        size_t o = (((size_t)b * NSEG + g) * DS_ + s) * DI_ + d;
        float prev = hseg[o];
        hseg[o] = h;
        h = exp2f(A2 * dtsum[((size_t)b * NSEG + g) * DI_ + d]) * h + prev;
    }
}

// Pass 3: re-scan with correct h_in; write y (fused D-skip + silu(z) gate).
__global__ __launch_bounds__(256)
void scan_part2(const float* __restrict__ dtb,
                const __hip_bfloat16* __restrict__ ub,
                const __hip_bfloat16* __restrict__ zs,
                const float* __restrict__ dbcF,
                const float* __restrict__ A_log,
                const float* __restrict__ Dskip,
                const float* __restrict__ hseg,
                __hip_bfloat16* __restrict__ yb)
{
    __shared__ float sdt[CT][256];
    __shared__ __hip_bfloat16 su[CT][256], sz[CT][256];
    __shared__ float sB[CT][DS_], sC[CT][DS_];
    int t = threadIdx.x;
    int d0 = blockIdx.x * 256, seg = blockIdx.y, b = blockIdx.z;
    int d = d0 + t;
    float A2[DS_], h[DS_];
    #pragma unroll
    for (int s = 0; s < DS_; ++s) {
        A2[s] = -__expf(A_log[d * DS_ + s]) * LOG2E;
        h[s] = hseg[(((size_t)b * NSEG + seg) * DS_ + s) * DI_ + d];
    }
    float Dd = Dskip[d];
    size_t rowbase = (size_t)b * L_ + seg * SEGLEN;
    for (int c = 0; c < SEGLEN / CT; ++c) {
        #pragma unroll
        for (int p = 0; p < CT; ++p) {
            size_t r = rowbase + c * CT + p;
            sdt[p][t] = dtb[r * DI_ + d];
            su[p][t]  = ub[r * DI_ + d];
            sz[p][t]  = zs[r * DI_ + d];
        }
        {
            int ll = t >> 4, ss = t & 15;
            size_t r = rowbase + c * CT + ll;
            sB[ll][ss] = dbcF[r * NDBC_ + DTR_ + ss];
            sC[ll][ss] = dbcF[r * NDBC_ + DTR_ + DS_ + ss];
        }
        __syncthreads();
        for (int l = 0; l < CT; ++l) {
            float dtv = sdt[l][t];
            float uu  = __bfloat162float(su[l][t]);
            float du  = dtv * uu;
            float y = 0.f;
            #pragma unroll
            for (int s = 0; s < DS_; ++s) {
                h[s] = exp2f(dtv * A2[s]) * h[s] + du * sB[l][s];
                y = fmaf(h[s], sC[l][s], y);
            }
            y = (y + Dd * uu) * __bfloat162float(sz[l][t]);
            size_t r = rowbase + c * CT + l;
            yb[r * DI_ + d] = __float2bfloat16(y);
        }
        __syncthreads();
    }
}

extern "C" void kernel_launch(void* const* d_in, const int* in_sizes, int n_in,
                              void* d_out, int out_size, void* d_ws, size_t ws_size,
                              hipStream_t stream)
{
    (void)in_sizes; (void)n_in; (void)out_size; (void)ws_size;
    const float* x     = (const float*)d_in[0];
    const float* gamma = (const float*)d_in[1];
    const float* beta  = (const float*)d_in[2];
    float* out = (float*)d_out;

    const size_t BLDI = (size_t)B_ * L_ * DI_;      // 8,388,608
    float* ws    = (float*)d_ws;
    float* dt    = ws;                               // 33.55 MB
    float* dbcF  = dt + BLDI;                        // 1.57 MB
    float* dtsum = dbcF + (size_t)B_ * L_ * NDBC_;   // 1.05 MB
    float* hseg  = dtsum + (size_t)B_ * NSEG * DI_;  // 16.78 MB
    __hip_bfloat16* lnb  = (__hip_bfloat16*)(hseg + (size_t)B_ * NSEG * DI_ * DS_);
    __hip_bfloat16* u0b  = lnb + (size_t)B_ * L_ * DM_;
    __hip_bfloat16* ub   = u0b + BLDI;
    __hip_bfloat16* zs   = ub + BLDI;
    __hip_bfloat16* yb   = zs + BLDI;                // 16.78 MB
    __hip_bfloat16* wb   = yb + BLDI;                // in_w / out_w (reused)
    __hip_bfloat16* xpwb = wb + (size_t)NXZ_ * DM_;
    __hip_bfloat16* dtwb = xpwb + (size_t)NDBC_ * DI_;
    __hip_bfloat16* dbcB = dtwb + (size_t)DI_ * DTR_;
    float* pbuf = (float*)yb;   // xproj split-K partials alias yb (both 16.78MB;
                                // pbuf dead before scan_part2 writes yb)

    dim3 blk(256);
    ln_kernel<<<B_ * L_, blk, 0, stream>>>(x, gamma, beta, lnb);

    for (int dir = 0; dir < 2; ++dir) {
        int base = 3 + dir * 9;
        const float* in_w    = (const float*)d_in[base + 0];
        const float* conv_w  = (const float*)d_in[base + 1];
        const float* conv_b  = (const float*)d_in[base + 2];
        const float* xproj_w = (const float*)d_in[base + 3];
        const float* dt_w    = (const float*)d_in[base + 4];
        const float* dt_b    = (const float*)d_in[base + 5];
        const float* A_log   = (const float*)d_in[base + 6];
        const float* Dsk     = (const float*)d_in[base + 7];
        const float* out_w   = (const float*)d_in[base + 8];

        cvt_kernel<<<(NXZ_ * DM_) / 1024, blk, 0, stream>>>(in_w, wb, NXZ_ * DM_);
        // in_proj: [u0b | silu(z)->zs] = ln(flip?) @ in_w^T
        mfma_gemm<<<dim3(NXZ_ / GBM, (B_ * L_) / GBM), blk, 0, stream>>>(
            lnb, DM_, wb, DM_, DM_, DM_, NXZ_, dir, 0, nullptr, nullptr, u0b, zs);

        conv_kernel<<<(B_ * L_ * DI_) / 256, blk, 0, stream>>>(u0b, conv_w, conv_b, ub);

        cvt_kernel<<<(NDBC_ * DI_) / 1024, blk, 0, stream>>>(xproj_w, xpwb, NDBC_ * DI_);
        // xproj: dbc = u @ xproj_w^T (N=96, clamped tile), split-K x8 -> partials
        mfma_gemm<<<dim3(1, (B_ * L_) / GBM, KS_), blk, 0, stream>>>(
            ub, DI_, xpwb, DI_, DI_, DI_ / KS_, NDBC_, 0, 3, nullptr, pbuf, nullptr, nullptr);
        xproj_reduce<<<(B_ * L_ * 128) / 256, blk, 0, stream>>>(pbuf, dbcF, dbcB);

        cvt_kernel<<<(DI_ * DTR_) / 1024, blk, 0, stream>>>(dt_w, dtwb, DI_ * DTR_);
        // dt = softplus(dbc[:, :64] @ dt_w^T + dt_b)
        mfma_gemm<<<dim3(DI_ / GBM, (B_ * L_) / GBM), blk, 0, stream>>>(
            dbcB, DTR_, dtwb, DTR_, DTR_, DTR_, DI_, 0, 4, dt_b, dt, nullptr, nullptr);

        // segmented scan (thread-per-channel, states in registers)
        scan_part1<<<dim3(DI_ / 256, NSEG, B_), blk, 0, stream>>>(
            dt, ub, dbcF, A_log, hseg, dtsum);
        seg_scan<<<(B_ * DI_ * DS_) / 256, blk, 0, stream>>>(hseg, dtsum, A_log);
        scan_part2<<<dim3(DI_ / 256, NSEG, B_), blk, 0, stream>>>(
            dt, ub, zs, dbcF, A_log, Dsk, hseg, yb);

        cvt_kernel<<<(DM_ * DI_) / 1024, blk, 0, stream>>>(out_w, wb, DM_ * DI_);
        // out_proj + residual combine
        mfma_gemm<<<dim3(DM_ / GBM, (B_ * L_) / GBM), blk, 0, stream>>>(
            yb, DI_, wb, DI_, DI_, DI_, DM_, 0, dir ? 2 : 1, x, out, nullptr, nullptr);
    }
}

// Round 5
// 764.582 us; speedup vs baseline: 5.5268x; 1.2211x over previous
//
#include <hip/hip_runtime.h>
#include <hip/hip_bf16.h>
#include <math.h>

// Problem constants
#define B_    2
#define L_    2048
#define DM_   1024      // d_model
#define DI_   2048      // d_inner
#define DS_   16        // d_state
#define DTR_  64        // dt_rank
#define NXZ_  4096      // 2*d_inner
#define NDBC_ 96        // dt_rank + 2*d_state

#define NSEG   64
#define SEGLEN 32
#define CT     16       // timesteps staged per chunk
#define KS_    8        // xproj split-K factor

#define LOG2E 1.4426950408889634f

typedef __attribute__((ext_vector_type(8))) short bf16x8;
typedef __attribute__((ext_vector_type(4))) float f32x4;

__device__ __forceinline__ void gload_lds16(const void* g, void* l) {
    __builtin_amdgcn_global_load_lds(
        (const __attribute__((address_space(1))) void*)g,
        (__attribute__((address_space(3))) void*)l,
        16, 0, 0);
}

// ---------------- LayerNorm (one block per row) -> bf16 out ----------------
__global__ __launch_bounds__(256)
void ln_kernel(const float* __restrict__ x,
               const float* __restrict__ gamma,
               const float* __restrict__ beta,
               __hip_bfloat16* __restrict__ out)
{
    int row = blockIdx.x;
    int t = threadIdx.x;
    const float* xr = x + (size_t)row * DM_;
    float4 v = ((const float4*)xr)[t];
    float s  = v.x + v.y + v.z + v.w;
    float ss = v.x*v.x + v.y*v.y + v.z*v.z + v.w*v.w;
    #pragma unroll
    for (int m = 1; m < 64; m <<= 1) {
        s  += __shfl_xor(s,  m, 64);
        ss += __shfl_xor(ss, m, 64);
    }
    __shared__ float as_[4], ass_[4];
    int w = t >> 6;
    if ((t & 63) == 0) { as_[w] = s; ass_[w] = ss; }
    __syncthreads();
    s  = as_[0] + as_[1] + as_[2] + as_[3];
    ss = ass_[0] + ass_[1] + ass_[2] + ass_[3];
    float mu  = s * (1.0f / DM_);
    float var = ss * (1.0f / DM_) - mu * mu;
    float inv = rsqrtf(var + 1e-5f);
    float4 g  = ((const float4*)gamma)[t];
    float4 bt = ((const float4*)beta)[t];
    __hip_bfloat16 ob[4];
    ob[0] = __float2bfloat16((v.x - mu) * inv * g.x + bt.x);
    ob[1] = __float2bfloat16((v.y - mu) * inv * g.y + bt.y);
    ob[2] = __float2bfloat16((v.z - mu) * inv * g.z + bt.z);
    ob[3] = __float2bfloat16((v.w - mu) * inv * g.w + bt.w);
    ((ushort4*)(out + (size_t)row * DM_))[t] = *(const ushort4*)ob;
}

// ---------------- weight converts (hoisted, both dirs) ----------------
__global__ __launch_bounds__(256)
void cvt2_kernel(const float* __restrict__ s0, const float* __restrict__ s1,
                 __hip_bfloat16* __restrict__ d, int n)
{
    int i = (blockIdx.x * 256 + threadIdx.x) * 4;
    const float* s = (i < n) ? s0 : s1;
    int j = (i < n) ? i : i - n;
    float4 v = *(const float4*)(s + j);
    __hip_bfloat16 ob[4];
    ob[0] = __float2bfloat16(v.x);
    ob[1] = __float2bfloat16(v.y);
    ob[2] = __float2bfloat16(v.z);
    ob[3] = __float2bfloat16(v.w);
    *(ushort4*)(d + i) = *(const ushort4*)ob;
}

// builds w_cat [DM_][2*DI_]: cols 0..DI-1 = fw, DI..2DI-1 = bw
__global__ __launch_bounds__(256)
void cvt_outw_kernel(const float* __restrict__ s0, const float* __restrict__ s1,
                     __hip_bfloat16* __restrict__ d)
{
    int j = (blockIdx.x * 256 + threadIdx.x) * 4;   // dst index
    int n = j >> 12;
    int c = j & 4095;
    int dir = c >> 11;
    int k = c & 2047;
    const float* s = dir ? s1 : s0;
    float4 v = *(const float4*)(s + (size_t)n * DI_ + k);
    __hip_bfloat16 ob[4];
    ob[0] = __float2bfloat16(v.x);
    ob[1] = __float2bfloat16(v.y);
    ob[2] = __float2bfloat16(v.z);
    ob[3] = __float2bfloat16(v.w);
    *(ushort4*)(d + j) = *(const ushort4*)ob;
}

// ---------------- bf16 MFMA GEMM: C = A(MxK) @ W(NxK)^T ----------------
// 128x128 tile, BK=64, 2-phase double-buffered global_load_lds staging,
// counted vmcnt (loads stay in flight across barriers), XOR-swizzled LDS.
// epi: 0=in_proj split, 1=out merged (+x resid), 3=xproj split-K partial,
//      4=dt softplus -> fp16
#define GBM 128
#define GBK 64
__global__ __launch_bounds__(256)
void mfma_gemm(const __hip_bfloat16* __restrict__ A, int lda,
               const __hip_bfloat16* __restrict__ W, int ldw,
               int K, int Kslice, int Nw, int flipA, int epi,
               const float* __restrict__ aux,
               float* __restrict__ out0,
               __hip_bfloat16* __restrict__ ob1,
               __hip_bfloat16* __restrict__ ob2,
               _Float16* __restrict__ oh)
{
    __shared__ __hip_bfloat16 smA[2][GBM * GBK];   // 2 x 16 KB
    __shared__ __hip_bfloat16 smB[2][GBM * GBK];   // 2 x 16 KB
    int t = threadIdx.x;
    int lane = t & 63, wid = t >> 6;
    int wm = wid >> 1, wn = wid & 1;
    int m0 = blockIdx.y * GBM, n0 = blockIdx.x * GBM;
    int kz = blockIdx.z;
    int k_begin = kz * Kslice;
    int k_end   = (k_begin + Kslice < K) ? (k_begin + Kslice) : K;
    int ktiles  = (k_end - k_begin) / GBK;

    f32x4 acc[4][4];
    #pragma unroll
    for (int i = 0; i < 4; ++i)
        #pragma unroll
        for (int j = 0; j < 4; ++j)
            acc[i][j] = (f32x4){0.f, 0.f, 0.f, 0.f};

    int arows[4], brows[4], cbs[4];
    #pragma unroll
    for (int p = 0; p < 4; ++p) {
        int o = p * 4096 + t * 16;
        int l = o ^ (((o >> 7) & 7) << 4);
        int r = l >> 7, cb = l & 127;
        int gr = m0 + r;
        if (flipA) gr = (gr & ~(L_ - 1)) | ((L_ - 1) - (gr & (L_ - 1)));
        arows[p] = gr;
        int wr = n0 + r; if (wr >= Nw) wr = Nw - 1;   // clamp (N=96 case)
        brows[p] = wr;
        cbs[p] = cb;
    }

    // 8 global_load_lds per STAGE (4 A + 4 B)
    #define STAGE(buf, k0)                                                        \
        {                                                                         \
            _Pragma("unroll")                                                     \
            for (int p = 0; p < 4; ++p) {                                         \
                int o = p * 4096 + t * 16;                                        \
                const char* gA = (const char*)(A + (size_t)arows[p] * lda + (k0)) \
                                 + cbs[p];                                        \
                gload_lds16(gA, (char*)&smA[buf][0] + o);                         \
                const char* gB = (const char*)(W + (size_t)brows[p] * ldw + (k0)) \
                                 + cbs[p];                                        \
                gload_lds16(gB, (char*)&smB[buf][0] + o);                         \
            }                                                                     \
        }

    STAGE(0, k_begin);
    int pb = 0;
    for (int kt = 0; kt < ktiles; ++kt) {
        if (kt + 1 < ktiles) {
            STAGE(pb ^ 1, k_begin + (kt + 1) * GBK);
            asm volatile("s_waitcnt vmcnt(8)" ::: "memory");  // cur's 8 done
        } else {
            asm volatile("s_waitcnt vmcnt(0)" ::: "memory");
        }
        __builtin_amdgcn_s_barrier();

        #pragma unroll
        for (int ks = 0; ks < 2; ++ks) {
            bf16x8 af[4], bfv[4];
            #pragma unroll
            for (int f = 0; f < 4; ++f) {
                int rowA = wm * 64 + f * 16 + (lane & 15);
                int lA = rowA * 128 + ks * 64 + ((lane >> 4) << 4);
                int pA = lA ^ ((rowA & 7) << 4);
                af[f] = *(const bf16x8*)((const char*)&smA[pb][0] + pA);
                int rowB = wn * 64 + f * 16 + (lane & 15);
                int lB = rowB * 128 + ks * 64 + ((lane >> 4) << 4);
                int pB = lB ^ ((rowB & 7) << 4);
                bfv[f] = *(const bf16x8*)((const char*)&smB[pb][0] + pB);
            }
            #pragma unroll
            for (int i = 0; i < 4; ++i)
                #pragma unroll
                for (int j = 0; j < 4; ++j)
                    acc[i][j] = __builtin_amdgcn_mfma_f32_16x16x32_bf16(
                        af[i], bfv[j], acc[i][j], 0, 0, 0);
        }
        __builtin_amdgcn_s_barrier();   // all waves done reading buf pb
        pb ^= 1;
    }

    // Epilogue. C/D layout: col = lane&15, row = (lane>>4)*4 + reg.
    #pragma unroll
    for (int i = 0; i < 4; ++i) {
        #pragma unroll
        for (int j = 0; j < 4; ++j) {
            f32x4 a4 = acc[i][j];
            int gn = n0 + wn * 64 + j * 16 + (lane & 15);
            #pragma unroll
            for (int r = 0; r < 4; ++r) {
                int gm = m0 + wm * 64 + i * 16 + ((lane >> 4) << 2) + r;
                float v = a4[r];
                if (epi == 0) {
                    if (gn < DI_) {
                        ob1[(size_t)gm * DI_ + gn] = __float2bfloat16(v);
                    } else {
                        float sv = v / (1.f + __expf(-v));
                        ob2[(size_t)gm * DI_ + (gn - DI_)] = __float2bfloat16(sv);
                    }
                } else if (epi == 1) {
                    out0[(size_t)gm * DM_ + gn] = aux[(size_t)gm * DM_ + gn] + 0.5f * v;
                } else if (epi == 3) {
                    // split-K partial, padded ldc=128 (cols >=96 are garbage)
                    out0[((size_t)kz * (B_ * L_) + gm) * 128 + gn] = v;
                } else { // epi == 4: dt softplus -> fp16
                    v += aux[gn];
                    float sp = (v > 20.f) ? v : log1pf(__expf(v));
                    oh[(size_t)gm * DI_ + gn] = (_Float16)sp;
                }
            }
        }
    }
    #undef STAGE
}

// ---------------- xproj split-K reduce ----------------
__global__ __launch_bounds__(256)
void xproj_reduce(const float* __restrict__ pbuf,
                  float* __restrict__ dbcF,
                  __hip_bfloat16* __restrict__ dbcB)
{
    int idx = blockIdx.x * 256 + threadIdx.x;   // (B*L) * 128
    int n = idx & 127, m = idx >> 7;
    float sum = 0.f;
    #pragma unroll
    for (int k = 0; k < KS_; ++k)
        sum += pbuf[((size_t)k * (B_ * L_) + m) * 128 + n];
    if (n < NDBC_) dbcF[(size_t)m * NDBC_ + n] = sum;
    if (n < DTR_)  dbcB[(size_t)m * DTR_ + n] = __float2bfloat16(sum);
}

// ---------------- Causal depthwise conv (width 4) + bias + SiLU ----------------
__global__ __launch_bounds__(256)
void conv_kernel(const __hip_bfloat16* __restrict__ u0,
                 const float* __restrict__ cw,
                 const float* __restrict__ cb,
                 __hip_bfloat16* __restrict__ u)
{
    int e = blockIdx.x * 256 + threadIdx.x;   // B*L*DI
    int d = e & (DI_ - 1);
    int l = (e >> 11) & (L_ - 1);
    size_t base = (size_t)(e - (l << 11) - d) + d;   // == (b*L)*DI + d
    float4 wv = ((const float4*)cw)[d];
    float acc = cb[d];
    if (l >= 3) acc += wv.x * __bfloat162float(u0[base + (size_t)(l - 3) * DI_]);
    if (l >= 2) acc += wv.y * __bfloat162float(u0[base + (size_t)(l - 2) * DI_]);
    if (l >= 1) acc += wv.z * __bfloat162float(u0[base + (size_t)(l - 1) * DI_]);
    acc += wv.w * __bfloat162float(u0[base + (size_t)l * DI_]);
    u[e] = __float2bfloat16(acc / (1.f + __expf(-acc)));   // silu
}

// ---------------- Segmented selective scan: thread-per-channel ----------------
// Pass 1: per-segment local scan from h=0; store final h + sum(dt).
__global__ __launch_bounds__(256)
void scan_part1(const _Float16* __restrict__ dtb,
                const __hip_bfloat16* __restrict__ ub,
                const float* __restrict__ dbcF,
                const float* __restrict__ A_log,
                float* __restrict__ hseg,     // [b][seg][s][DI]
                float* __restrict__ dtsum)    // [b][seg][DI]
{
    __shared__ float sdt[CT][256];
    __shared__ __hip_bfloat16 su[CT][256];
    __shared__ float sB[CT][DS_];
    int t = threadIdx.x;
    int d0 = blockIdx.x * 256, seg = blockIdx.y, b = blockIdx.z;
    int d = d0 + t;
    float A2[DS_], h[DS_];
    #pragma unroll
    for (int s = 0; s < DS_; ++s) {
        A2[s] = -__expf(A_log[d * DS_ + s]) * LOG2E;
        h[s] = 0.f;
    }
    float dts = 0.f;
    size_t rowbase = (size_t)b * L_ + seg * SEGLEN;
    for (int c = 0; c < SEGLEN / CT; ++c) {
        #pragma unroll
        for (int p = 0; p < CT; ++p) {
            size_t r = rowbase + c * CT + p;
            sdt[p][t] = (float)dtb[r * DI_ + d];
            su[p][t]  = ub[r * DI_ + d];
        }
        {
            int ll = t >> 4, ss = t & 15;
            sB[ll][ss] = dbcF[(rowbase + c * CT + ll) * NDBC_ + DTR_ + ss];
        }
        __syncthreads();
        for (int l = 0; l < CT; ++l) {
            float dtv = sdt[l][t];
            float du  = dtv * __bfloat162float(su[l][t]);
            dts += dtv;
            #pragma unroll
            for (int s = 0; s < DS_; ++s)
                h[s] = exp2f(dtv * A2[s]) * h[s] + du * sB[l][s];
        }
        __syncthreads();
    }
    #pragma unroll
    for (int s = 0; s < DS_; ++s)
        hseg[(((size_t)b * NSEG + seg) * DS_ + s) * DI_ + d] = h[s];
    dtsum[((size_t)b * NSEG + seg) * DI_ + d] = dts;
}

// Pass 2: inter-segment scan with load-ahead prefetch.
__global__ __launch_bounds__(256)
void seg_scan(float* __restrict__ hseg,
              const float* __restrict__ dtsum,
              const float* __restrict__ A_log)
{
    int idx = blockIdx.x * 256 + threadIdx.x;   // b*DI*DS, d fastest
    int d = idx & (DI_ - 1);
    int s = (idx >> 11) & 15;
    int b = idx >> 15;
    float A2 = -__expf(A_log[d * DS_ + s]) * LOG2E;
    float h = 0.f;
    size_t o = (((size_t)b * NSEG + 0) * DS_ + s) * DI_ + d;
    size_t oi = ((size_t)b * NSEG + 0) * DI_ + d;
    float pv = hseg[o], ds = dtsum[oi];
    for (int g = 0; g < NSEG; ++g) {
        float npv = 0.f, nds = 0.f;
        if (g + 1 < NSEG) {
            npv = hseg[o + (size_t)DS_ * DI_];
            nds = dtsum[oi + DI_];
        }
        hseg[o] = h;
        h = exp2f(A2 * ds) * h + pv;
        pv = npv; ds = nds;
        o += (size_t)DS_ * DI_;
        oi += DI_;
    }
}

// Pass 3: re-scan with correct h_in; write y into yb_cat[row][dir*DI+d],
// bw rows written pre-flipped so out_proj is a single K-concat GEMM.
__global__ __launch_bounds__(256)
void scan_part2(const _Float16* __restrict__ dtb,
                const __hip_bfloat16* __restrict__ ub,
                const __hip_bfloat16* __restrict__ zs,
                const float* __restrict__ dbcF,
                const float* __restrict__ A_log,
                const float* __restrict__ Dskip,
                const float* __restrict__ hseg,
                __hip_bfloat16* __restrict__ ycat,
                int dir)
{
    __shared__ float sdt[CT][256];
    __shared__ __hip_bfloat16 su[CT][256], sz[CT][256];
    __shared__ float sB[CT][DS_], sC[CT][DS_];
    int t = threadIdx.x;
    int d0 = blockIdx.x * 256, seg = blockIdx.y, b = blockIdx.z;
    int d = d0 + t;
    float A2[DS_], h[DS_];
    #pragma unroll
    for (int s = 0; s < DS_; ++s) {
        A2[s] = -__expf(A_log[d * DS_ + s]) * LOG2E;
        h[s] = hseg[(((size_t)b * NSEG + seg) * DS_ + s) * DI_ + d];
    }
    float Dd = Dskip[d];
    size_t rowbase = (size_t)b * L_ + seg * SEGLEN;
    int ycol = dir * DI_ + d;
    for (int c = 0; c < SEGLEN / CT; ++c) {
        #pragma unroll
        for (int p = 0; p < CT; ++p) {
            size_t r = rowbase + c * CT + p;
            sdt[p][t] = (float)dtb[r * DI_ + d];
            su[p][t]  = ub[r * DI_ + d];
            sz[p][t]  = zs[r * DI_ + d];
        }
        {
            int ll = t >> 4, ss = t & 15;
            size_t r = rowbase + c * CT + ll;
            sB[ll][ss] = dbcF[r * NDBC_ + DTR_ + ss];
            sC[ll][ss] = dbcF[r * NDBC_ + DTR_ + DS_ + ss];
        }
        __syncthreads();
        for (int l = 0; l < CT; ++l) {
            float dtv = sdt[l][t];
            float uu  = __bfloat162float(su[l][t]);
            float du  = dtv * uu;
            float y = 0.f;
            #pragma unroll
            for (int s = 0; s < DS_; ++s) {
                h[s] = exp2f(dtv * A2[s]) * h[s] + du * sB[l][s];
                y = fmaf(h[s], sC[l][s], y);
            }
            y = (y + Dd * uu) * __bfloat162float(sz[l][t]);
            int lg = seg * SEGLEN + c * CT + l;
            int lw = dir ? (L_ - 1 - lg) : lg;
            ycat[((size_t)b * L_ + lw) * NXZ_ + ycol] = __float2bfloat16(y);
        }
        __syncthreads();
    }
}

extern "C" void kernel_launch(void* const* d_in, const int* in_sizes, int n_in,
                              void* d_out, int out_size, void* d_ws, size_t ws_size,
                              hipStream_t stream)
{
    (void)in_sizes; (void)n_in; (void)out_size; (void)ws_size;
    const float* x     = (const float*)d_in[0];
    const float* gamma = (const float*)d_in[1];
    const float* beta  = (const float*)d_in[2];
    float* out = (float*)d_out;

    const size_t BLDI = (size_t)B_ * L_ * DI_;      // 8,388,608

    // workspace (~139 MB), u0/pbuf/dtF time-share one 16.78MB region per dir
    float* ws    = (float*)d_ws;
    float* dbcF  = ws;                               // 1.57 MB
    float* dtsum = dbcF + (size_t)B_ * L_ * NDBC_;   // 1.05 MB
    float* hseg  = dtsum + (size_t)B_ * NSEG * DI_;  // 16.78 MB
    float* shreg = hseg + (size_t)B_ * NSEG * DI_ * DS_;  // 16.78 MB shared region
    __hip_bfloat16* lnb  = (__hip_bfloat16*)(shreg + BLDI / 2 * 2);
    __hip_bfloat16* ub   = lnb + (size_t)B_ * L_ * DM_;   // 16.78
    __hip_bfloat16* zs   = ub + BLDI;                     // 16.78
    __hip_bfloat16* ycat = zs + BLDI;                     // 33.55 (both dirs, K-cat)
    __hip_bfloat16* win  = ycat + (size_t)B_ * L_ * NXZ_; // 16.78 (both dirs)
    __hip_bfloat16* wocat= win + (size_t)2 * NXZ_ * DM_;  // 8.39  ([DM][2*DI])
    __hip_bfloat16* xpw  = wocat + (size_t)DM_ * NXZ_;    // 0.79 (both dirs)
    __hip_bfloat16* dtw  = xpw + (size_t)2 * NDBC_ * DI_; // 0.53 (both dirs)
    __hip_bfloat16* dbcB = dtw + (size_t)2 * DI_ * DTR_;  // 0.52 (per-dir reuse)
    // aliases of shreg (sequential lifetimes within each dir):
    __hip_bfloat16* u0b  = (__hip_bfloat16*)shreg;   // in_proj -> conv
    float*          pbuf = shreg;                    // xproj partials -> reduce
    _Float16*       dtF  = (_Float16*)shreg;         // dt gemm -> scans

    dim3 blk(256);

    // weights -> bf16, all up front
    cvt2_kernel<<<(2 * NXZ_ * DM_) / 1024, blk, 0, stream>>>(
        (const float*)d_in[3], (const float*)d_in[12], win, NXZ_ * DM_);
    cvt_outw_kernel<<<(DM_ * NXZ_) / 1024, blk, 0, stream>>>(
        (const float*)d_in[11], (const float*)d_in[20], wocat);
    cvt2_kernel<<<(2 * NDBC_ * DI_) / 1024, blk, 0, stream>>>(
        (const float*)d_in[6], (const float*)d_in[15], xpw, NDBC_ * DI_);
    cvt2_kernel<<<(2 * DI_ * DTR_) / 1024, blk, 0, stream>>>(
        (const float*)d_in[7], (const float*)d_in[16], dtw, DI_ * DTR_);

    ln_kernel<<<B_ * L_, blk, 0, stream>>>(x, gamma, beta, lnb);

    for (int dir = 0; dir < 2; ++dir) {
        int base = 3 + dir * 9;
        const float* conv_w  = (const float*)d_in[base + 1];
        const float* conv_b  = (const float*)d_in[base + 2];
        const float* dt_b    = (const float*)d_in[base + 5];
        const float* A_log   = (const float*)d_in[base + 6];
        const float* Dsk     = (const float*)d_in[base + 7];

        // in_proj: [u0b | silu(z)->zs] = ln(flip?) @ in_w^T
        mfma_gemm<<<dim3(NXZ_ / GBM, (B_ * L_) / GBM), blk, 0, stream>>>(
            lnb, DM_, win + (size_t)dir * NXZ_ * DM_, DM_,
            DM_, DM_, NXZ_, dir, 0, nullptr, nullptr, u0b, zs, nullptr);

        conv_kernel<<<(B_ * L_ * DI_) / 256, blk, 0, stream>>>(u0b, conv_w, conv_b, ub);

        // xproj: dbc = u @ xproj_w^T (N=96), split-K x8 -> pbuf (shreg)
        mfma_gemm<<<dim3(1, (B_ * L_) / GBM, KS_), blk, 0, stream>>>(
            ub, DI_, xpw + (size_t)dir * NDBC_ * DI_, DI_,
            DI_, DI_ / KS_, NDBC_, 0, 3, nullptr, pbuf, nullptr, nullptr, nullptr);
        xproj_reduce<<<(B_ * L_ * 128) / 256, blk, 0, stream>>>(pbuf, dbcF, dbcB);

        // dt = softplus(dbc[:, :64] @ dt_w^T + dt_b) -> fp16 (shreg)
        mfma_gemm<<<dim3(DI_ / GBM, (B_ * L_) / GBM), blk, 0, stream>>>(
            dbcB, DTR_, dtw + (size_t)dir * DI_ * DTR_, DTR_,
            DTR_, DTR_, DI_, 0, 4, dt_b, nullptr, nullptr, nullptr, dtF);

        // segmented scan (thread-per-channel, states in registers)
        scan_part1<<<dim3(DI_ / 256, NSEG, B_), blk, 0, stream>>>(
            dtF, ub, dbcF, A_log, hseg, dtsum);
        seg_scan<<<(B_ * DI_ * DS_) / 256, blk, 0, stream>>>(hseg, dtsum, A_log);
        scan_part2<<<dim3(DI_ / 256, NSEG, B_), blk, 0, stream>>>(
            dtF, ub, zs, dbcF, A_log, Dsk, hseg, ycat, dir);
    }

    // merged out_proj: out = x + 0.5 * (ycat @ wocat^T), K = 2*DI
    mfma_gemm<<<dim3(DM_ / GBM, (B_ * L_) / GBM), blk, 0, stream>>>(
        ycat, NXZ_, wocat, NXZ_, NXZ_, NXZ_, DM_, 0, 1,
        x, out, nullptr, nullptr, nullptr);
}

// Round 7
// 473.209 us; speedup vs baseline: 8.9299x; 1.6157x over previous
//
#include <hip/hip_runtime.h>
#include <hip/hip_bf16.h>
#include <math.h>

// Problem constants
#define B_    2
#define L_    2048
#define DM_   1024      // d_model
#define DI_   2048      // d_inner
#define DS_   16        // d_state
#define DTR_  64        // dt_rank
#define NXZ_  4096      // 2*d_inner
#define NDBC_ 96        // dt_rank + 2*d_state

#define NSEG   64
#define SEGLEN 32
#define CT     16       // timesteps staged per chunk
#define KS_    8        // xproj split-K factor

#define LOG2E 1.4426950408889634f

typedef __attribute__((ext_vector_type(8))) short bf16x8;
typedef __attribute__((ext_vector_type(4))) float f32x4;

__device__ __forceinline__ void gload_lds16(const void* g, void* l) {
    __builtin_amdgcn_global_load_lds(
        (const __attribute__((address_space(1))) void*)g,
        (__attribute__((address_space(3))) void*)l,
        16, 0, 0);
}

// ---------------- LayerNorm (one block per row) -> bf16 out ----------------
__global__ __launch_bounds__(256)
void ln_kernel(const float* __restrict__ x,
               const float* __restrict__ gamma,
               const float* __restrict__ beta,
               __hip_bfloat16* __restrict__ out)
{
    int row = blockIdx.x;
    int t = threadIdx.x;
    const float* xr = x + (size_t)row * DM_;
    float4 v = ((const float4*)xr)[t];
    float s  = v.x + v.y + v.z + v.w;
    float ss = v.x*v.x + v.y*v.y + v.z*v.z + v.w*v.w;
    #pragma unroll
    for (int m = 1; m < 64; m <<= 1) {
        s  += __shfl_xor(s,  m, 64);
        ss += __shfl_xor(ss, m, 64);
    }
    __shared__ float as_[4], ass_[4];
    int w = t >> 6;
    if ((t & 63) == 0) { as_[w] = s; ass_[w] = ss; }
    __syncthreads();
    s  = as_[0] + as_[1] + as_[2] + as_[3];
    ss = ass_[0] + ass_[1] + ass_[2] + ass_[3];
    float mu  = s * (1.0f / DM_);
    float var = ss * (1.0f / DM_) - mu * mu;
    float inv = rsqrtf(var + 1e-5f);
    float4 g  = ((const float4*)gamma)[t];
    float4 bt = ((const float4*)beta)[t];
    __hip_bfloat16 ob[4];
    ob[0] = __float2bfloat16((v.x - mu) * inv * g.x + bt.x);
    ob[1] = __float2bfloat16((v.y - mu) * inv * g.y + bt.y);
    ob[2] = __float2bfloat16((v.z - mu) * inv * g.z + bt.z);
    ob[3] = __float2bfloat16((v.w - mu) * inv * g.w + bt.w);
    ((ushort4*)(out + (size_t)row * DM_))[t] = *(const ushort4*)ob;
}

// ---------------- weight converts (hoisted, both dirs) ----------------
__global__ __launch_bounds__(256)
void cvt2_kernel(const float* __restrict__ s0, const float* __restrict__ s1,
                 __hip_bfloat16* __restrict__ d, int n)
{
    int i = (blockIdx.x * 256 + threadIdx.x) * 4;
    const float* s = (i < n) ? s0 : s1;
    int j = (i < n) ? i : i - n;
    float4 v = *(const float4*)(s + j);
    __hip_bfloat16 ob[4];
    ob[0] = __float2bfloat16(v.x);
    ob[1] = __float2bfloat16(v.y);
    ob[2] = __float2bfloat16(v.z);
    ob[3] = __float2bfloat16(v.w);
    *(ushort4*)(d + i) = *(const ushort4*)ob;
}

// builds w_cat [DM_][2*DI_]: cols 0..DI-1 = fw, DI..2DI-1 = bw
__global__ __launch_bounds__(256)
void cvt_outw_kernel(const float* __restrict__ s0, const float* __restrict__ s1,
                     __hip_bfloat16* __restrict__ d)
{
    int j = (blockIdx.x * 256 + threadIdx.x) * 4;   // dst index
    int n = j >> 12;
    int c = j & 4095;
    int dir = c >> 11;
    int k = c & 2047;
    const float* s = dir ? s1 : s0;
    float4 v = *(const float4*)(s + (size_t)n * DI_ + k);
    __hip_bfloat16 ob[4];
    ob[0] = __float2bfloat16(v.x);
    ob[1] = __float2bfloat16(v.y);
    ob[2] = __float2bfloat16(v.z);
    ob[3] = __float2bfloat16(v.w);
    *(ushort4*)(d + j) = *(const ushort4*)ob;
}

// ---------------- bf16 MFMA GEMM: C = A(MxK) @ W(NxK)^T ----------------
// 128x128 tile, BK=64. DBUF=1: double-buffered staging + counted vmcnt.
// EPI: 0=in_proj split (LDS-coalesced bf16 out), 1=out merged (+x resid),
//      3=xproj split-K partial, 4=dt fast-softplus -> fp16 (LDS-coalesced)
#define GBM 128
#define GBK 64
#define EPLD 132   // padded LDS row (elements) for the epilogue tile

template<int DBUF, int EPI>
__global__ __launch_bounds__(256)
void mfma_gemm(const __hip_bfloat16* __restrict__ A, int lda,
               const __hip_bfloat16* __restrict__ W, int ldw,
               int K, int Kslice, int Nw, int flipA,
               const float* __restrict__ aux,
               float* __restrict__ out0,
               __hip_bfloat16* __restrict__ ob1,
               __hip_bfloat16* __restrict__ ob2,
               _Float16* __restrict__ oh)
{
    // layout: [A0][A1][B0][B1] (DBUF) or [A0][B0]; epilogue reuses smem.
    __shared__ __attribute__((aligned(16))) char smem[DBUF ? 65536 : 33792];
    const int BOFF = DBUF ? 32768 : 16384;
    int t = threadIdx.x;
    int lane = t & 63, wid = t >> 6;
    int wm = wid >> 1, wn = wid & 1;
    int m0 = blockIdx.y * GBM, n0 = blockIdx.x * GBM;
    int kz = blockIdx.z;
    int k_begin = kz * Kslice;
    int k_end   = (k_begin + Kslice < K) ? (k_begin + Kslice) : K;
    int ktiles  = (k_end - k_begin) / GBK;

    f32x4 acc[4][4];
    #pragma unroll
    for (int i = 0; i < 4; ++i)
        #pragma unroll
        for (int j = 0; j < 4; ++j)
            acc[i][j] = (f32x4){0.f, 0.f, 0.f, 0.f};

    int arows[4], brows[4], cbs[4];
    #pragma unroll
    for (int p = 0; p < 4; ++p) {
        int o = p * 4096 + t * 16;
        int l = o ^ (((o >> 7) & 7) << 4);
        int r = l >> 7, cb = l & 127;
        int gr = m0 + r;
        if (flipA) gr = (gr & ~(L_ - 1)) | ((L_ - 1) - (gr & (L_ - 1)));
        arows[p] = gr;
        int wr = n0 + r; if (wr >= Nw) wr = Nw - 1;   // clamp (N=96 case)
        brows[p] = wr;
        cbs[p] = cb;
    }

    #define STAGE(buf, k0)                                                        \
        {                                                                         \
            _Pragma("unroll")                                                     \
            for (int p = 0; p < 4; ++p) {                                         \
                int o = p * 4096 + t * 16;                                        \
                const char* gA = (const char*)(A + (size_t)arows[p] * lda + (k0)) \
                                 + cbs[p];                                        \
                gload_lds16(gA, smem + (buf) * 16384 + o);                        \
                const char* gB = (const char*)(W + (size_t)brows[p] * ldw + (k0)) \
                                 + cbs[p];                                        \
                gload_lds16(gB, smem + BOFF + (buf) * 16384 + o);                 \
            }                                                                     \
        }

    auto compute_tile = [&](int pbv) {
        char* bA = smem + pbv * 16384;
        char* bB = smem + BOFF + pbv * 16384;
        #pragma unroll
        for (int ks = 0; ks < 2; ++ks) {
            bf16x8 af[4], bfv[4];
            #pragma unroll
            for (int f = 0; f < 4; ++f) {
                int rowA = wm * 64 + f * 16 + (lane & 15);
                int lA = rowA * 128 + ks * 64 + ((lane >> 4) << 4);
                int pA = lA ^ ((rowA & 7) << 4);
                af[f] = *(const bf16x8*)(bA + pA);
                int rowB = wn * 64 + f * 16 + (lane & 15);
                int lB = rowB * 128 + ks * 64 + ((lane >> 4) << 4);
                int pB = lB ^ ((rowB & 7) << 4);
                bfv[f] = *(const bf16x8*)(bB + pB);
            }
            #pragma unroll
            for (int i = 0; i < 4; ++i)
                #pragma unroll
                for (int j = 0; j < 4; ++j)
                    acc[i][j] = __builtin_amdgcn_mfma_f32_16x16x32_bf16(
                        af[i], bfv[j], acc[i][j], 0, 0, 0);
        }
    };

    if (DBUF) {
        STAGE(0, k_begin);
        int pb = 0;
        for (int kt = 0; kt < ktiles; ++kt) {
            if (kt + 1 < ktiles) {
                STAGE(pb ^ 1, k_begin + (kt + 1) * GBK);
                asm volatile("s_waitcnt vmcnt(8)" ::: "memory");
            } else {
                asm volatile("s_waitcnt vmcnt(0)" ::: "memory");
            }
            __builtin_amdgcn_s_barrier();
            compute_tile(pb);
            __builtin_amdgcn_s_barrier();
            pb ^= 1;
        }
    } else {
        for (int kt = 0; kt < ktiles; ++kt) {
            STAGE(0, k_begin + kt * GBK);
            asm volatile("s_waitcnt vmcnt(0)" ::: "memory");
            __builtin_amdgcn_s_barrier();
            compute_tile(0);
            __builtin_amdgcn_s_barrier();
        }
    }
    #undef STAGE

    // Epilogue. C/D layout: col = lane&15, row = (lane>>4)*4 + reg.
    if (EPI == 0) {
        // in_proj: block-uniform half select; LDS-coalesced bf16 store
        bool zh = (n0 >= DI_);
        __hip_bfloat16* tile = (__hip_bfloat16*)smem;
        #pragma unroll
        for (int i = 0; i < 4; ++i)
            #pragma unroll
            for (int j = 0; j < 4; ++j) {
                int col = wn * 64 + j * 16 + (lane & 15);
                #pragma unroll
                for (int r = 0; r < 4; ++r) {
                    int row = wm * 64 + i * 16 + ((lane >> 4) << 2) + r;
                    float v = acc[i][j][r];
                    if (zh) v = v / (1.f + __expf(-v));
                    tile[row * EPLD + col] = __float2bfloat16(v);
                }
            }
        __syncthreads();
        __hip_bfloat16* dst = zh ? ob2 : ob1;
        int nb = zh ? n0 - DI_ : n0;
        #pragma unroll
        for (int it = 0; it < 8; ++it) {
            int row = it * 16 + (t >> 4);
            int c8 = (t & 15) * 8;
            bf16x8 vv = *(const bf16x8*)&tile[row * EPLD + c8];
            *(bf16x8*)(dst + (size_t)(m0 + row) * DI_ + nb + c8) = vv;
        }
    } else if (EPI == 4) {
        // dt: bias + fast softplus -> fp16, LDS-coalesced store
        _Float16* tile = (_Float16*)smem;
        float bias_j[4];
        #pragma unroll
        for (int j = 0; j < 4; ++j)
            bias_j[j] = aux[n0 + wn * 64 + j * 16 + (lane & 15)];
        #pragma unroll
        for (int i = 0; i < 4; ++i)
            #pragma unroll
            for (int j = 0; j < 4; ++j) {
                int col = wn * 64 + j * 16 + (lane & 15);
                #pragma unroll
                for (int r = 0; r < 4; ++r) {
                    int row = wm * 64 + i * 16 + ((lane >> 4) << 2) + r;
                    float v = acc[i][j][r] + bias_j[j];
                    float sp = fmaxf(v, 0.f) + __logf(1.f + __expf(-fabsf(v)));
                    tile[row * EPLD + col] = (_Float16)sp;
                }
            }
        __syncthreads();
        #pragma unroll
        for (int it = 0; it < 8; ++it) {
            int row = it * 16 + (t >> 4);
            int c8 = (t & 15) * 8;
            bf16x8 vv = *(const bf16x8*)&tile[row * EPLD + c8];
            *(bf16x8*)(oh + (size_t)(m0 + row) * DI_ + n0 + c8) = vv;
        }
    } else {
        #pragma unroll
        for (int i = 0; i < 4; ++i) {
            #pragma unroll
            for (int j = 0; j < 4; ++j) {
                f32x4 a4 = acc[i][j];
                int gn = n0 + wn * 64 + j * 16 + (lane & 15);
                #pragma unroll
                for (int r = 0; r < 4; ++r) {
                    int gm = m0 + wm * 64 + i * 16 + ((lane >> 4) << 2) + r;
                    float v = a4[r];
                    if (EPI == 1) {
                        out0[(size_t)gm * DM_ + gn] =
                            aux[(size_t)gm * DM_ + gn] + 0.5f * v;
                    } else { // EPI == 3: split-K partial, padded ldc=128
                        out0[((size_t)kz * (B_ * L_) + gm) * 128 + gn] = v;
                    }
                }
            }
        }
    }
}

// ---------------- xproj split-K reduce ----------------
__global__ __launch_bounds__(256)
void xproj_reduce(const float* __restrict__ pbuf,
                  float* __restrict__ dbcF,
                  __hip_bfloat16* __restrict__ dbcB)
{
    int idx = blockIdx.x * 256 + threadIdx.x;   // (B*L) * 128
    int n = idx & 127, m = idx >> 7;
    float sum = 0.f;
    #pragma unroll
    for (int k = 0; k < KS_; ++k)
        sum += pbuf[((size_t)k * (B_ * L_) + m) * 128 + n];
    if (n < NDBC_) dbcF[(size_t)m * NDBC_ + n] = sum;
    if (n < DTR_)  dbcB[(size_t)m * DTR_ + n] = __float2bfloat16(sum);
}

// ---------------- Causal depthwise conv (width 4) + bias + SiLU ----------------
__global__ __launch_bounds__(256)
void conv_kernel(const __hip_bfloat16* __restrict__ u0,
                 const float* __restrict__ cw,
                 const float* __restrict__ cb,
                 __hip_bfloat16* __restrict__ u)
{
    int e = blockIdx.x * 256 + threadIdx.x;   // B*L*DI
    int d = e & (DI_ - 1);
    int l = (e >> 11) & (L_ - 1);
    size_t base = (size_t)(e - (l << 11) - d) + d;   // == (b*L)*DI + d
    float4 wv = ((const float4*)cw)[d];
    float acc = cb[d];
    if (l >= 3) acc += wv.x * __bfloat162float(u0[base + (size_t)(l - 3) * DI_]);
    if (l >= 2) acc += wv.y * __bfloat162float(u0[base + (size_t)(l - 2) * DI_]);
    if (l >= 1) acc += wv.z * __bfloat162float(u0[base + (size_t)(l - 1) * DI_]);
    acc += wv.w * __bfloat162float(u0[base + (size_t)l * DI_]);
    u[e] = __float2bfloat16(acc / (1.f + __expf(-acc)));   // silu
}

// ---------------- Segmented selective scan: thread-per-channel ----------------
// Pass 1: per-segment local scan from h=0; store final h + sum(dt).
__global__ __launch_bounds__(256)
void scan_part1(const _Float16* __restrict__ dtb,
                const __hip_bfloat16* __restrict__ ub,
                const float* __restrict__ dbcF,
                const float* __restrict__ A_log,
                float* __restrict__ hseg,     // [b][seg][s][DI]
                float* __restrict__ dtsum)    // [b][seg][DI]
{
    __shared__ float sdt[CT][256];
    __shared__ __hip_bfloat16 su[CT][256];
    __shared__ float sB[CT][DS_];
    int t = threadIdx.x;
    int d0 = blockIdx.x * 256, seg = blockIdx.y, b = blockIdx.z;
    int d = d0 + t;
    float A2[DS_], h[DS_];
    #pragma unroll
    for (int s = 0; s < DS_; ++s) {
        A2[s] = -__expf(A_log[d * DS_ + s]) * LOG2E;
        h[s] = 0.f;
    }
    float dts = 0.f;
    size_t rowbase = (size_t)b * L_ + seg * SEGLEN;
    for (int c = 0; c < SEGLEN / CT; ++c) {
        #pragma unroll
        for (int p = 0; p < CT; ++p) {
            size_t r = rowbase + c * CT + p;
            sdt[p][t] = (float)dtb[r * DI_ + d];
            su[p][t]  = ub[r * DI_ + d];
        }
        {
            int ll = t >> 4, ss = t & 15;
            sB[ll][ss] = dbcF[(rowbase + c * CT + ll) * NDBC_ + DTR_ + ss];
        }
        __syncthreads();
        for (int l = 0; l < CT; ++l) {
            float dtv = sdt[l][t];
            float du  = dtv * __bfloat162float(su[l][t]);
            dts += dtv;
            #pragma unroll
            for (int s = 0; s < DS_; ++s)
                h[s] = exp2f(dtv * A2[s]) * h[s] + du * sB[l][s];
        }
        __syncthreads();
    }
    #pragma unroll
    for (int s = 0; s < DS_; ++s)
        hseg[(((size_t)b * NSEG + seg) * DS_ + s) * DI_ + d] = h[s];
    dtsum[((size_t)b * NSEG + seg) * DI_ + d] = dts;
}

// Pass 2: inter-segment scan with load-ahead prefetch.
__global__ __launch_bounds__(256)
void seg_scan(float* __restrict__ hseg,
              const float* __restrict__ dtsum,
              const float* __restrict__ A_log)
{
    int idx = blockIdx.x * 256 + threadIdx.x;   // b*DI*DS, d fastest
    int d = idx & (DI_ - 1);
    int s = (idx >> 11) & 15;
    int b = idx >> 15;
    float A2 = -__expf(A_log[d * DS_ + s]) * LOG2E;
    float h = 0.f;
    size_t o = (((size_t)b * NSEG + 0) * DS_ + s) * DI_ + d;
    size_t oi = ((size_t)b * NSEG + 0) * DI_ + d;
    float pv = hseg[o], ds = dtsum[oi];
    for (int g = 0; g < NSEG; ++g) {
        float npv = 0.f, nds = 0.f;
        if (g + 1 < NSEG) {
            npv = hseg[o + (size_t)DS_ * DI_];
            nds = dtsum[oi + DI_];
        }
        hseg[o] = h;
        h = exp2f(A2 * ds) * h + pv;
        pv = npv; ds = nds;
        o += (size_t)DS_ * DI_;
        oi += DI_;
    }
}

// Pass 3: re-scan with correct h_in; write y into yb_cat[row][dir*DI+d],
// bw rows written pre-flipped so out_proj is a single K-concat GEMM.
__global__ __launch_bounds__(256)
void scan_part2(const _Float16* __restrict__ dtb,
                const __hip_bfloat16* __restrict__ ub,
                const __hip_bfloat16* __restrict__ zs,
                const float* __restrict__ dbcF,
                const float* __restrict__ A_log,
                const float* __restrict__ Dskip,
                const float* __restrict__ hseg,
                __hip_bfloat16* __restrict__ ycat,
                int dir)
{
    __shared__ float sdt[CT][256];
    __shared__ __hip_bfloat16 su[CT][256], sz[CT][256];
    __shared__ float sB[CT][DS_], sC[CT][DS_];
    int t = threadIdx.x;
    int d0 = blockIdx.x * 256, seg = blockIdx.y, b = blockIdx.z;
    int d = d0 + t;
    float A2[DS_], h[DS_];
    #pragma unroll
    for (int s = 0; s < DS_; ++s) {
        A2[s] = -__expf(A_log[d * DS_ + s]) * LOG2E;
        h[s] = hseg[(((size_t)b * NSEG + seg) * DS_ + s) * DI_ + d];
    }
    float Dd = Dskip[d];
    size_t rowbase = (size_t)b * L_ + seg * SEGLEN;
    int ycol = dir * DI_ + d;
    for (int c = 0; c < SEGLEN / CT; ++c) {
        #pragma unroll
        for (int p = 0; p < CT; ++p) {
            size_t r = rowbase + c * CT + p;
            sdt[p][t] = (float)dtb[r * DI_ + d];
            su[p][t]  = ub[r * DI_ + d];
            sz[p][t]  = zs[r * DI_ + d];
        }
        {
            int ll = t >> 4, ss = t & 15;
            size_t r = rowbase + c * CT + ll;
            sB[ll][ss] = dbcF[r * NDBC_ + DTR_ + ss];
            sC[ll][ss] = dbcF[r * NDBC_ + DTR_ + DS_ + ss];
        }
        __syncthreads();
        for (int l = 0; l < CT; ++l) {
            float dtv = sdt[l][t];
            float uu  = __bfloat162float(su[l][t]);
            float du  = dtv * uu;
            float y = 0.f;
            #pragma unroll
            for (int s = 0; s < DS_; ++s) {
                h[s] = exp2f(dtv * A2[s]) * h[s] + du * sB[l][s];
                y = fmaf(h[s], sC[l][s], y);
            }
            y = (y + Dd * uu) * __bfloat162float(sz[l][t]);
            int lg = seg * SEGLEN + c * CT + l;
            int lw = dir ? (L_ - 1 - lg) : lg;
            ycat[((size_t)b * L_ + lw) * NXZ_ + ycol] = __float2bfloat16(y);
        }
        __syncthreads();
    }
}

extern "C" void kernel_launch(void* const* d_in, const int* in_sizes, int n_in,
                              void* d_out, int out_size, void* d_ws, size_t ws_size,
                              hipStream_t stream)
{
    (void)in_sizes; (void)n_in; (void)out_size; (void)ws_size;
    const float* x     = (const float*)d_in[0];
    const float* gamma = (const float*)d_in[1];
    const float* beta  = (const float*)d_in[2];
    float* out = (float*)d_out;

    const size_t BLDI = (size_t)B_ * L_ * DI_;      // 8,388,608

    // workspace (~139 MB), u0/pbuf/dtF time-share one 16.78MB region per dir
    float* ws    = (float*)d_ws;
    float* dbcF  = ws;                               // 1.57 MB
    float* dtsum = dbcF + (size_t)B_ * L_ * NDBC_;   // 1.05 MB
    float* hseg  = dtsum + (size_t)B_ * NSEG * DI_;  // 16.78 MB
    float* shreg = hseg + (size_t)B_ * NSEG * DI_ * DS_;  // 16.78 MB shared region
    __hip_bfloat16* lnb  = (__hip_bfloat16*)(shreg + BLDI / 2 * 2);
    __hip_bfloat16* ub   = lnb + (size_t)B_ * L_ * DM_;   // 16.78
    __hip_bfloat16* zs   = ub + BLDI;                     // 16.78
    __hip_bfloat16* ycat = zs + BLDI;                     // 33.55 (both dirs, K-cat)
    __hip_bfloat16* win  = ycat + (size_t)B_ * L_ * NXZ_; // 16.78 (both dirs)
    __hip_bfloat16* wocat= win + (size_t)2 * NXZ_ * DM_;  // 8.39  ([DM][2*DI])
    __hip_bfloat16* xpw  = wocat + (size_t)DM_ * NXZ_;    // 0.79 (both dirs)
    __hip_bfloat16* dtw  = xpw + (size_t)2 * NDBC_ * DI_; // 0.53 (both dirs)
    __hip_bfloat16* dbcB = dtw + (size_t)2 * DI_ * DTR_;  // 0.52 (per-dir reuse)
    // aliases of shreg (sequential lifetimes within each dir):
    __hip_bfloat16* u0b  = (__hip_bfloat16*)shreg;   // in_proj -> conv
    float*          pbuf = shreg;                    // xproj partials -> reduce
    _Float16*       dtF  = (_Float16*)shreg;         // dt gemm -> scans

    dim3 blk(256);

    // weights -> bf16, all up front
    cvt2_kernel<<<(2 * NXZ_ * DM_) / 1024, blk, 0, stream>>>(
        (const float*)d_in[3], (const float*)d_in[12], win, NXZ_ * DM_);
    cvt_outw_kernel<<<(DM_ * NXZ_) / 1024, blk, 0, stream>>>(
        (const float*)d_in[11], (const float*)d_in[20], wocat);
    cvt2_kernel<<<(2 * NDBC_ * DI_) / 1024, blk, 0, stream>>>(
        (const float*)d_in[6], (const float*)d_in[15], xpw, NDBC_ * DI_);
    cvt2_kernel<<<(2 * DI_ * DTR_) / 1024, blk, 0, stream>>>(
        (const float*)d_in[7], (const float*)d_in[16], dtw, DI_ * DTR_);

    ln_kernel<<<B_ * L_, blk, 0, stream>>>(x, gamma, beta, lnb);

    for (int dir = 0; dir < 2; ++dir) {
        int base = 3 + dir * 9;
        const float* conv_w  = (const float*)d_in[base + 1];
        const float* conv_b  = (const float*)d_in[base + 2];
        const float* dt_b    = (const float*)d_in[base + 5];
        const float* A_log   = (const float*)d_in[base + 6];
        const float* Dsk     = (const float*)d_in[base + 7];

        // in_proj: [u0b | silu(z)->zs] = ln(flip?) @ in_w^T
        mfma_gemm<1, 0><<<dim3(NXZ_ / GBM, (B_ * L_) / GBM), blk, 0, stream>>>(
            lnb, DM_, win + (size_t)dir * NXZ_ * DM_, DM_,
            DM_, DM_, NXZ_, dir, nullptr, nullptr, u0b, zs, nullptr);

        conv_kernel<<<(B_ * L_ * DI_) / 256, blk, 0, stream>>>(u0b, conv_w, conv_b, ub);

        // xproj: dbc = u @ xproj_w^T (N=96), split-K x8 -> pbuf (shreg)
        mfma_gemm<1, 3><<<dim3(1, (B_ * L_) / GBM, KS_), blk, 0, stream>>>(
            ub, DI_, xpw + (size_t)dir * NDBC_ * DI_, DI_,
            DI_, DI_ / KS_, NDBC_, 0, nullptr, pbuf, nullptr, nullptr, nullptr);
        xproj_reduce<<<(B_ * L_ * 128) / 256, blk, 0, stream>>>(pbuf, dbcF, dbcB);

        // dt = softplus(dbc[:, :64] @ dt_w^T + dt_b) -> fp16 (shreg)
        mfma_gemm<0, 4><<<dim3(DI_ / GBM, (B_ * L_) / GBM), blk, 0, stream>>>(
            dbcB, DTR_, dtw + (size_t)dir * DI_ * DTR_, DTR_,
            DTR_, DTR_, DI_, 0, dt_b, nullptr, nullptr, nullptr, dtF);

        // segmented scan (thread-per-channel, states in registers)
        scan_part1<<<dim3(DI_ / 256, NSEG, B_), blk, 0, stream>>>(
            dtF, ub, dbcF, A_log, hseg, dtsum);
        seg_scan<<<(B_ * DI_ * DS_) / 256, blk, 0, stream>>>(hseg, dtsum, A_log);
        scan_part2<<<dim3(DI_ / 256, NSEG, B_), blk, 0, stream>>>(
            dtF, ub, zs, dbcF, A_log, Dsk, hseg, ycat, dir);
    }

    // merged out_proj: out = x + 0.5 * (ycat @ wocat^T), K = 2*DI
    mfma_gemm<1, 1><<<dim3(DM_ / GBM, (B_ * L_) / GBM), blk, 0, stream>>>(
        ycat, NXZ_, wocat, NXZ_, NXZ_, NXZ_, DM_, 0,
        x, out, nullptr, nullptr, nullptr);
}